// Round 1
// baseline (2048.654 us; speedup 1.0000x reference)
//
#include <hip/hip_runtime.h>
#include <math.h>

// ---------------------------------------------------------------------------
// Problem constants: N=100000 nodes, E=1600000 edges, all feature dims = 128.
// N % 32 == 0 and (E*128) % 256 == 0, so tile kernels need no edge guards.
// ---------------------------------------------------------------------------

__device__ __forceinline__ float act_leaky_elu(float v) {
    // elu(leaky_relu(v, 0.01)), alpha=1
    float l = (v >= 0.0f) ? v : 0.01f * v;
    return (l > 0.0f) ? l : expm1f(l);
}

// Weighted in-degree + in-edge count (segment sums over col)
__global__ __launch_bounds__(256)
void k_deg(const int* __restrict__ ei, const float* __restrict__ ew,
           float* __restrict__ deg, float* __restrict__ cnt, int E) {
    int e = blockIdx.x * 256 + threadIdx.x;
    if (e < E) {
        int c = ei[E + e];
        atomicAdd(&deg[c], ew[e]);
        atomicAdd(&cnt[c], 1.0f);
    }
}

// dis = deg>0 ? rsqrt(max(deg,1e-12)) : 0 ;  icn = 1/max(cnt,1)
__global__ __launch_bounds__(256)
void k_dis(const float* __restrict__ deg, const float* __restrict__ cnt,
           float* __restrict__ dis, float* __restrict__ icn, int n) {
    int i = blockIdx.x * 256 + threadIdx.x;
    if (i < n) {
        float d = deg[i];
        dis[i] = (d > 0.0f) ? (1.0f / sqrtf(fmaxf(d, 1e-12f))) : 0.0f;
        icn[i] = 1.0f / fmaxf(cnt[i], 1.0f);
    }
}

// C[n,128] = A[n,128] @ W[128,128] (+ bias). 32 rows/block, 4x4 reg tile.
__global__ __launch_bounds__(256)
void k_gemm(const float* __restrict__ A, const float* __restrict__ W,
            const float* __restrict__ bias, float* __restrict__ C) {
    __shared__ float Wl[128 * 128];
    for (int i = threadIdx.x; i < 4096; i += 256)
        ((float4*)Wl)[i] = ((const float4*)W)[i];
    __syncthreads();
    const int tx = threadIdx.x & 31;   // 4 consecutive output cols: tx*4..tx*4+3
    const int ty = threadIdx.x >> 5;   // 8 row-groups of 4 rows
    const long row0 = (long)blockIdx.x * 32 + ty * 4;
    float4 bv = bias ? ((const float4*)bias)[tx] : make_float4(0.f, 0.f, 0.f, 0.f);
    float4 acc[4];
    acc[0] = bv; acc[1] = bv; acc[2] = bv; acc[3] = bv;
    const float* a = A + row0 * 128;
    #pragma unroll 4
    for (int k = 0; k < 128; ++k) {
        float4 wv = ((const float4*)(Wl + k * 128))[tx];
        #pragma unroll
        for (int i = 0; i < 4; ++i) {
            float av = a[i * 128 + k];
            acc[i].x = fmaf(av, wv.x, acc[i].x);
            acc[i].y = fmaf(av, wv.y, acc[i].y);
            acc[i].z = fmaf(av, wv.z, acc[i].z);
            acc[i].w = fmaf(av, wv.w, acc[i].w);
        }
    }
    #pragma unroll
    for (int i = 0; i < 4; ++i)
        ((float4*)(C + (row0 + i) * 128))[tx] = acc[i];
}

// Edge scatter: one thread per (edge, feature).
// agg[col] += norm * t[row] ; msg[col] += w * h[row]
__global__ __launch_bounds__(256)
void k_edge(const int* __restrict__ ei, const float* __restrict__ ew,
            const float* __restrict__ dis, const float* __restrict__ t,
            const float* __restrict__ h, float* __restrict__ agg,
            float* __restrict__ msg, int E) {
    unsigned tid = blockIdx.x * 256u + threadIdx.x;
    int e = tid >> 7;
    int f = tid & 127;
    if (e >= E) return;
    int r = ei[e];
    int c = ei[E + e];
    float wt = ew[e];
    float nrm = dis[r] * wt * dis[c];
    atomicAdd(&agg[(long)c * 128 + f], nrm * t[(long)r * 128 + f]);
    atomicAdd(&msg[(long)c * 128 + f], wt * h[(long)r * 128 + f]);
}

// out[:, 0:128] = relu(agg + h @ Wroot + b)   (elu(leaky(relu(x))) == relu(x))
__global__ __launch_bounds__(256)
void k_final_arma(const float* __restrict__ h, const float* __restrict__ agg,
                  const float* __restrict__ Wroot, const float* __restrict__ b,
                  float* __restrict__ out) {
    __shared__ float Wl[128 * 128];
    for (int i = threadIdx.x; i < 4096; i += 256)
        ((float4*)Wl)[i] = ((const float4*)Wroot)[i];
    __syncthreads();
    const int tx = threadIdx.x & 31;
    const int ty = threadIdx.x >> 5;
    const long row0 = (long)blockIdx.x * 32 + ty * 4;
    float4 bv = ((const float4*)b)[tx];
    float4 acc[4];
    acc[0] = bv; acc[1] = bv; acc[2] = bv; acc[3] = bv;
    const float* a = h + row0 * 128;
    #pragma unroll 4
    for (int k = 0; k < 128; ++k) {
        float4 wv = ((const float4*)(Wl + k * 128))[tx];
        #pragma unroll
        for (int i = 0; i < 4; ++i) {
            float av = a[i * 128 + k];
            acc[i].x = fmaf(av, wv.x, acc[i].x);
            acc[i].y = fmaf(av, wv.y, acc[i].y);
            acc[i].z = fmaf(av, wv.z, acc[i].z);
            acc[i].w = fmaf(av, wv.w, acc[i].w);
        }
    }
    #pragma unroll
    for (int i = 0; i < 4; ++i) {
        float4 g = ((const float4*)(agg + (row0 + i) * 128))[tx];
        float4 v;
        v.x = fmaxf(acc[i].x + g.x, 0.0f);
        v.y = fmaxf(acc[i].y + g.y, 0.0f);
        v.z = fmaxf(acc[i].z + g.z, 0.0f);
        v.w = fmaxf(acc[i].w + g.w, 0.0f);
        ((float4*)(out + (row0 + i) * 256))[tx] = v;
    }
}

// out[:, 128:256] = elu(leaky( (msg*icn) @ Wl + h @ Wr + bl ))
// Two phases sharing one 64 KiB LDS buffer (icn folds out of phase 1 since it
// is a per-row scalar: (msg*icn)@Wl == icn * (msg@Wl)).
__global__ __launch_bounds__(256)
void k_final_sage(const float* __restrict__ h, const float* __restrict__ msg,
                  const float* __restrict__ icn, const float* __restrict__ Wlw,
                  const float* __restrict__ Wrw, const float* __restrict__ bl,
                  float* __restrict__ out) {
    __shared__ float Wl[128 * 128];
    const int tx = threadIdx.x & 31;
    const int ty = threadIdx.x >> 5;
    const long row0 = (long)blockIdx.x * 32 + ty * 4;

    // phase 1: acc = msg @ Wl, then scale by icn
    for (int i = threadIdx.x; i < 4096; i += 256)
        ((float4*)Wl)[i] = ((const float4*)Wlw)[i];
    __syncthreads();
    float4 acc[4];
    acc[0] = acc[1] = acc[2] = acc[3] = make_float4(0.f, 0.f, 0.f, 0.f);
    {
        const float* m = msg + row0 * 128;
        #pragma unroll 4
        for (int k = 0; k < 128; ++k) {
            float4 wv = ((const float4*)(Wl + k * 128))[tx];
            #pragma unroll
            for (int i = 0; i < 4; ++i) {
                float mv = m[i * 128 + k];
                acc[i].x = fmaf(mv, wv.x, acc[i].x);
                acc[i].y = fmaf(mv, wv.y, acc[i].y);
                acc[i].z = fmaf(mv, wv.z, acc[i].z);
                acc[i].w = fmaf(mv, wv.w, acc[i].w);
            }
        }
    }
    #pragma unroll
    for (int i = 0; i < 4; ++i) {
        float s = icn[row0 + i];
        acc[i].x *= s; acc[i].y *= s; acc[i].z *= s; acc[i].w *= s;
    }
    __syncthreads();  // done reading Wl before overwrite

    // phase 2: acc += h @ Wr
    for (int i = threadIdx.x; i < 4096; i += 256)
        ((float4*)Wl)[i] = ((const float4*)Wrw)[i];
    __syncthreads();
    {
        const float* a = h + row0 * 128;
        #pragma unroll 4
        for (int k = 0; k < 128; ++k) {
            float4 wv = ((const float4*)(Wl + k * 128))[tx];
            #pragma unroll
            for (int i = 0; i < 4; ++i) {
                float av = a[i * 128 + k];
                acc[i].x = fmaf(av, wv.x, acc[i].x);
                acc[i].y = fmaf(av, wv.y, acc[i].y);
                acc[i].z = fmaf(av, wv.z, acc[i].z);
                acc[i].w = fmaf(av, wv.w, acc[i].w);
            }
        }
    }
    float4 bv = ((const float4*)bl)[tx];
    #pragma unroll
    for (int i = 0; i < 4; ++i) {
        float4 v;
        v.x = act_leaky_elu(acc[i].x + bv.x);
        v.y = act_leaky_elu(acc[i].y + bv.y);
        v.z = act_leaky_elu(acc[i].z + bv.z);
        v.w = act_leaky_elu(acc[i].w + bv.w);
        ((float4*)(out + (row0 + i) * 256 + 128))[tx] = v;
    }
}

extern "C" void kernel_launch(void* const* d_in, const int* in_sizes, int n_in,
                              void* d_out, int out_size, void* d_ws, size_t ws_size,
                              hipStream_t stream) {
    const float* x    = (const float*)d_in[0];
    const int*   ei   = (const int*)d_in[1];
    const float* ew   = (const float*)d_in[2];
    const float* Wpre = (const float*)d_in[3];
    const float* bpre = (const float*)d_in[4];
    const float* Wai  = (const float*)d_in[5];
    const float* War  = (const float*)d_in[6];
    const float* ab   = (const float*)d_in[7];
    const float* Wsl  = (const float*)d_in[8];
    const float* bsl  = (const float*)d_in[9];
    const float* Wsr  = (const float*)d_in[10];

    const int N = in_sizes[0] / 128;
    const int E = in_sizes[2];

    float* ws  = (float*)d_ws;
    float* h   = ws;                       // N*128
    float* t   = ws + (long)N * 128;       // N*128
    float* agg = ws + (long)2 * N * 128;   // N*128  (zeroed)
    float* msg = ws + (long)3 * N * 128;   // N*128  (zeroed)
    float* deg = ws + (long)4 * N * 128;   // N      (zeroed)
    float* cnt = deg + N;                  // N      (zeroed)
    float* dis = cnt + N;                  // N
    float* icn = dis + N;                  // N

    // zero agg, msg, deg, cnt in one contiguous memset
    hipMemsetAsync(agg, 0, ((size_t)2 * N * 128 + 2 * N) * sizeof(float), stream);

    k_deg<<<(E + 255) / 256, 256, 0, stream>>>(ei, ew, deg, cnt, E);
    k_dis<<<(N + 255) / 256, 256, 0, stream>>>(deg, cnt, dis, icn, N);

    const int gn = N / 32;  // N=100000 -> 3125 blocks, exact
    k_gemm<<<gn, 256, 0, stream>>>(x, Wpre, bpre, h);   // h = x@Wpre + bpre
    k_gemm<<<gn, 256, 0, stream>>>(h, Wai, nullptr, t); // t = h@Wai

    const long tot = (long)E * 128;       // 204.8M threads, exact /256
    k_edge<<<(int)(tot / 256), 256, 0, stream>>>(ei, ew, dis, t, h, agg, msg, E);

    k_final_arma<<<gn, 256, 0, stream>>>(h, agg, War, ab, (float*)d_out);
    k_final_sage<<<gn, 256, 0, stream>>>(h, msg, icn, Wsl, Wsr, bsl, (float*)d_out);
}

// Round 2
// 1101.227 us; speedup vs baseline: 1.8603x; 1.8603x over previous
//
#include <hip/hip_runtime.h>
#include <math.h>

// ---------------------------------------------------------------------------
// N=100000 nodes, E=1600000 edges, dims all 128.
// Round 2: CSR build + pull-side aggregation (no atomics on feature arrays).
// ---------------------------------------------------------------------------

__device__ __forceinline__ float act_leaky_elu(float v) {
    float l = (v >= 0.0f) ? v : 0.01f * v;
    return (l > 0.0f) ? l : expm1f(l);
}

// Weighted in-degree (float) + in-edge count (int), segment sums over col
__global__ __launch_bounds__(256)
void k_deg(const int* __restrict__ ei, const float* __restrict__ ew,
           float* __restrict__ deg, int* __restrict__ cnti, int E) {
    int e = blockIdx.x * 256 + threadIdx.x;
    if (e < E) {
        int c = ei[E + e];
        atomicAdd(&deg[c], ew[e]);
        atomicAdd(&cnti[c], 1);
    }
}

// dis = deg>0 ? rsqrt(max(deg,1e-12)) : 0 ;  icn = 1/max(cnt,1)
__global__ __launch_bounds__(256)
void k_dis(const float* __restrict__ deg, const int* __restrict__ cnti,
           float* __restrict__ dis, float* __restrict__ icn, int n) {
    int i = blockIdx.x * 256 + threadIdx.x;
    if (i < n) {
        float d = deg[i];
        dis[i] = (d > 0.0f) ? (1.0f / sqrtf(fmaxf(d, 1e-12f))) : 0.0f;
        icn[i] = 1.0f / fmaxf((float)cnti[i], 1.0f);
    }
}

// ---- hierarchical exclusive scan over n ints (n <= 128*1024) ----
__global__ __launch_bounds__(256)
void k_scan1(const int* __restrict__ in, int* __restrict__ out,
             int* __restrict__ blksum, int n) {
    __shared__ int sh[256];
    const int tid = threadIdx.x;
    const int idx = blockIdx.x * 1024 + tid * 4;
    int v0 = (idx + 0 < n) ? in[idx + 0] : 0;
    int v1 = (idx + 1 < n) ? in[idx + 1] : 0;
    int v2 = (idx + 2 < n) ? in[idx + 2] : 0;
    int v3 = (idx + 3 < n) ? in[idx + 3] : 0;
    int tsum = v0 + v1 + v2 + v3;
    sh[tid] = tsum;
    __syncthreads();
    #pragma unroll
    for (int off = 1; off < 256; off <<= 1) {
        int add = (tid >= off) ? sh[tid - off] : 0;
        __syncthreads();
        sh[tid] += add;
        __syncthreads();
    }
    int excl = sh[tid] - tsum;
    if (idx + 0 < n) out[idx + 0] = excl;
    if (idx + 1 < n) out[idx + 1] = excl + v0;
    if (idx + 2 < n) out[idx + 2] = excl + v0 + v1;
    if (idx + 3 < n) out[idx + 3] = excl + v0 + v1 + v2;
    if (tid == 255) blksum[blockIdx.x] = sh[255];
}

__global__ __launch_bounds__(128)
void k_scan2(int* __restrict__ blksum, int nb) {
    __shared__ int sh[128];
    const int tid = threadIdx.x;
    int orig = (tid < nb) ? blksum[tid] : 0;
    sh[tid] = orig;
    __syncthreads();
    #pragma unroll
    for (int off = 1; off < 128; off <<= 1) {
        int add = (tid >= off) ? sh[tid - off] : 0;
        __syncthreads();
        sh[tid] += add;
        __syncthreads();
    }
    if (tid < nb) blksum[tid] = sh[tid] - orig;
}

__global__ __launch_bounds__(256)
void k_scan3(int* __restrict__ out, const int* __restrict__ blksum, int n) {
    const int add = blksum[blockIdx.x];
    const int base = blockIdx.x * 1024 + threadIdx.x;
    #pragma unroll
    for (int i = 0; i < 4; ++i) {
        int idx = base + i * 256;
        if (idx < n) out[idx] += add;
    }
}

// scatter edges into CSR slots; precompute per-edge norm
__global__ __launch_bounds__(256)
void k_scatter(const int* __restrict__ ei, const float* __restrict__ ew,
               const float* __restrict__ dis, const int* __restrict__ rowp,
               int* __restrict__ fill, int* __restrict__ srcs,
               float* __restrict__ nrm, float* __restrict__ wts, int E) {
    int e = blockIdx.x * 256 + threadIdx.x;
    if (e < E) {
        int r = ei[e];
        int c = ei[E + e];
        float w = ew[e];
        int pos = rowp[c] + atomicAdd(&fill[c], 1);
        srcs[pos] = r;
        nrm[pos]  = dis[r] * w * dis[c];
        wts[pos]  = w;
    }
}

// Pull aggregation: one wave per node, 64 lanes x float2 = 128 features.
// agg[n] = sum nrm*t[src] ; msg[n] = sum w*h[src]. No atomics, single write.
__global__ __launch_bounds__(256)
void k_pull(const int* __restrict__ rowp, const int* __restrict__ srcs,
            const float* __restrict__ nrm, const float* __restrict__ wts,
            const float* __restrict__ t, const float* __restrict__ h,
            float* __restrict__ agg, float* __restrict__ msg, int N) {
    const int node = blockIdx.x * 4 + (threadIdx.x >> 6);
    if (node >= N) return;
    const int lane = threadIdx.x & 63;
    const int s = rowp[node];
    const int eEnd = rowp[node + 1];
    float2 aA = make_float2(0.f, 0.f);
    float2 aM = make_float2(0.f, 0.f);
    int e = s;
    for (; e + 1 < eEnd; e += 2) {
        int   r0 = srcs[e],     r1 = srcs[e + 1];
        float n0 = nrm[e],      n1 = nrm[e + 1];
        float w0 = wts[e],      w1 = wts[e + 1];
        float2 t0 = ((const float2*)(t + (size_t)r0 * 128))[lane];
        float2 h0 = ((const float2*)(h + (size_t)r0 * 128))[lane];
        float2 t1 = ((const float2*)(t + (size_t)r1 * 128))[lane];
        float2 h1 = ((const float2*)(h + (size_t)r1 * 128))[lane];
        aA.x = fmaf(n0, t0.x, aA.x); aA.y = fmaf(n0, t0.y, aA.y);
        aM.x = fmaf(w0, h0.x, aM.x); aM.y = fmaf(w0, h0.y, aM.y);
        aA.x = fmaf(n1, t1.x, aA.x); aA.y = fmaf(n1, t1.y, aA.y);
        aM.x = fmaf(w1, h1.x, aM.x); aM.y = fmaf(w1, h1.y, aM.y);
    }
    if (e < eEnd) {
        int   r0 = srcs[e];
        float n0 = nrm[e];
        float w0 = wts[e];
        float2 t0 = ((const float2*)(t + (size_t)r0 * 128))[lane];
        float2 h0 = ((const float2*)(h + (size_t)r0 * 128))[lane];
        aA.x = fmaf(n0, t0.x, aA.x); aA.y = fmaf(n0, t0.y, aA.y);
        aM.x = fmaf(w0, h0.x, aM.x); aM.y = fmaf(w0, h0.y, aM.y);
    }
    ((float2*)(agg + (size_t)node * 128))[lane] = aA;
    ((float2*)(msg + (size_t)node * 128))[lane] = aM;
}

// Fallback push-scatter (used only if ws too small for CSR arrays)
__global__ __launch_bounds__(256)
void k_edge(const int* __restrict__ ei, const float* __restrict__ ew,
            const float* __restrict__ dis, const float* __restrict__ t,
            const float* __restrict__ h, float* __restrict__ agg,
            float* __restrict__ msg, int E) {
    unsigned tid = blockIdx.x * 256u + threadIdx.x;
    int e = tid >> 7;
    int f = tid & 127;
    if (e >= E) return;
    int r = ei[e];
    int c = ei[E + e];
    float wt = ew[e];
    float nr = dis[r] * wt * dis[c];
    atomicAdd(&agg[(size_t)c * 128 + f], nr * t[(size_t)r * 128 + f]);
    atomicAdd(&msg[(size_t)c * 128 + f], wt * h[(size_t)r * 128 + f]);
}

// C[n,128] = A[n,128] @ W[128,128] (+ bias). 32 rows/block, 4x4 reg tile.
__global__ __launch_bounds__(256)
void k_gemm(const float* __restrict__ A, const float* __restrict__ W,
            const float* __restrict__ bias, float* __restrict__ C) {
    __shared__ float Wl[128 * 128];
    for (int i = threadIdx.x; i < 4096; i += 256)
        ((float4*)Wl)[i] = ((const float4*)W)[i];
    __syncthreads();
    const int tx = threadIdx.x & 31;
    const int ty = threadIdx.x >> 5;
    const size_t row0 = (size_t)blockIdx.x * 32 + ty * 4;
    float4 bv = bias ? ((const float4*)bias)[tx] : make_float4(0.f, 0.f, 0.f, 0.f);
    float4 acc[4];
    acc[0] = bv; acc[1] = bv; acc[2] = bv; acc[3] = bv;
    const float* a = A + row0 * 128;
    #pragma unroll 4
    for (int k = 0; k < 128; ++k) {
        float4 wv = ((const float4*)(Wl + k * 128))[tx];
        #pragma unroll
        for (int i = 0; i < 4; ++i) {
            float av = a[i * 128 + k];
            acc[i].x = fmaf(av, wv.x, acc[i].x);
            acc[i].y = fmaf(av, wv.y, acc[i].y);
            acc[i].z = fmaf(av, wv.z, acc[i].z);
            acc[i].w = fmaf(av, wv.w, acc[i].w);
        }
    }
    #pragma unroll
    for (int i = 0; i < 4; ++i)
        ((float4*)(C + (row0 + i) * 128))[tx] = acc[i];
}

// out[:, 0:128] = relu(agg + h @ Wroot + b)
__global__ __launch_bounds__(256)
void k_final_arma(const float* __restrict__ h, const float* __restrict__ agg,
                  const float* __restrict__ Wroot, const float* __restrict__ b,
                  float* __restrict__ out) {
    __shared__ float Wl[128 * 128];
    for (int i = threadIdx.x; i < 4096; i += 256)
        ((float4*)Wl)[i] = ((const float4*)Wroot)[i];
    __syncthreads();
    const int tx = threadIdx.x & 31;
    const int ty = threadIdx.x >> 5;
    const size_t row0 = (size_t)blockIdx.x * 32 + ty * 4;
    float4 bv = ((const float4*)b)[tx];
    float4 acc[4];
    acc[0] = bv; acc[1] = bv; acc[2] = bv; acc[3] = bv;
    const float* a = h + row0 * 128;
    #pragma unroll 4
    for (int k = 0; k < 128; ++k) {
        float4 wv = ((const float4*)(Wl + k * 128))[tx];
        #pragma unroll
        for (int i = 0; i < 4; ++i) {
            float av = a[i * 128 + k];
            acc[i].x = fmaf(av, wv.x, acc[i].x);
            acc[i].y = fmaf(av, wv.y, acc[i].y);
            acc[i].z = fmaf(av, wv.z, acc[i].z);
            acc[i].w = fmaf(av, wv.w, acc[i].w);
        }
    }
    #pragma unroll
    for (int i = 0; i < 4; ++i) {
        float4 g = ((const float4*)(agg + (row0 + i) * 128))[tx];
        float4 v;
        v.x = fmaxf(acc[i].x + g.x, 0.0f);
        v.y = fmaxf(acc[i].y + g.y, 0.0f);
        v.z = fmaxf(acc[i].z + g.z, 0.0f);
        v.w = fmaxf(acc[i].w + g.w, 0.0f);
        ((float4*)(out + (row0 + i) * 256))[tx] = v;
    }
}

// out[:, 128:256] = elu(leaky( icn*(msg @ Wl) + h @ Wr + bl ))
__global__ __launch_bounds__(256)
void k_final_sage(const float* __restrict__ h, const float* __restrict__ msg,
                  const float* __restrict__ icn, const float* __restrict__ Wlw,
                  const float* __restrict__ Wrw, const float* __restrict__ bl,
                  float* __restrict__ out) {
    __shared__ float Wl[128 * 128];
    const int tx = threadIdx.x & 31;
    const int ty = threadIdx.x >> 5;
    const size_t row0 = (size_t)blockIdx.x * 32 + ty * 4;

    for (int i = threadIdx.x; i < 4096; i += 256)
        ((float4*)Wl)[i] = ((const float4*)Wlw)[i];
    __syncthreads();
    float4 acc[4];
    acc[0] = acc[1] = acc[2] = acc[3] = make_float4(0.f, 0.f, 0.f, 0.f);
    {
        const float* m = msg + row0 * 128;
        #pragma unroll 4
        for (int k = 0; k < 128; ++k) {
            float4 wv = ((const float4*)(Wl + k * 128))[tx];
            #pragma unroll
            for (int i = 0; i < 4; ++i) {
                float mv = m[i * 128 + k];
                acc[i].x = fmaf(mv, wv.x, acc[i].x);
                acc[i].y = fmaf(mv, wv.y, acc[i].y);
                acc[i].z = fmaf(mv, wv.z, acc[i].z);
                acc[i].w = fmaf(mv, wv.w, acc[i].w);
            }
        }
    }
    #pragma unroll
    for (int i = 0; i < 4; ++i) {
        float s = icn[row0 + i];
        acc[i].x *= s; acc[i].y *= s; acc[i].z *= s; acc[i].w *= s;
    }
    __syncthreads();

    for (int i = threadIdx.x; i < 4096; i += 256)
        ((float4*)Wl)[i] = ((const float4*)Wrw)[i];
    __syncthreads();
    {
        const float* a = h + row0 * 128;
        #pragma unroll 4
        for (int k = 0; k < 128; ++k) {
            float4 wv = ((const float4*)(Wl + k * 128))[tx];
            #pragma unroll
            for (int i = 0; i < 4; ++i) {
                float av = a[i * 128 + k];
                acc[i].x = fmaf(av, wv.x, acc[i].x);
                acc[i].y = fmaf(av, wv.y, acc[i].y);
                acc[i].z = fmaf(av, wv.z, acc[i].z);
                acc[i].w = fmaf(av, wv.w, acc[i].w);
            }
        }
    }
    float4 bv = ((const float4*)bl)[tx];
    #pragma unroll
    for (int i = 0; i < 4; ++i) {
        float4 v;
        v.x = act_leaky_elu(acc[i].x + bv.x);
        v.y = act_leaky_elu(acc[i].y + bv.y);
        v.z = act_leaky_elu(acc[i].z + bv.z);
        v.w = act_leaky_elu(acc[i].w + bv.w);
        ((float4*)(out + (row0 + i) * 256 + 128))[tx] = v;
    }
}

extern "C" void kernel_launch(void* const* d_in, const int* in_sizes, int n_in,
                              void* d_out, int out_size, void* d_ws, size_t ws_size,
                              hipStream_t stream) {
    const float* x    = (const float*)d_in[0];
    const int*   ei   = (const int*)d_in[1];
    const float* ew   = (const float*)d_in[2];
    const float* Wpre = (const float*)d_in[3];
    const float* bpre = (const float*)d_in[4];
    const float* Wai  = (const float*)d_in[5];
    const float* War  = (const float*)d_in[6];
    const float* ab   = (const float*)d_in[7];
    const float* Wsl  = (const float*)d_in[8];
    const float* bsl  = (const float*)d_in[9];
    const float* Wsr  = (const float*)d_in[10];

    const int N = in_sizes[0] / 128;
    const int E = in_sizes[2];
    const size_t NF = (size_t)N * 128;

    float* ws   = (float*)d_ws;
    float* h    = ws;
    float* t    = h + NF;
    float* agg  = t + NF;
    float* msg  = agg + NF;
    float* deg  = msg + NF;                 // N
    float* dis  = deg + N;                  // N
    float* icn  = dis + N;                  // N
    int*   cnti = (int*)(icn + N);          // N+1
    int*   fill = cnti + (N + 1);           // N
    int*   rowp = fill + N;                 // N+1
    int*   blks = rowp + (N + 1);           // 128
    int*   srcs = blks + 128;               // E
    float* nrm  = (float*)(srcs + E);       // E
    float* wts  = nrm + E;                  // E

    const size_t need_csr = (size_t)((float*)(wts + E) - ws) * sizeof(float);
    const bool use_csr = ws_size >= need_csr;

    const int gn = (N + 31) / 32;
    const int ge = (E + 255) / 256;

    if (use_csr) {
        // zero deg..fill (contiguous): deg,dis,icn (3N floats) + cnti,fill (2N+1 ints)
        hipMemsetAsync(deg, 0, ((size_t)5 * N + 1) * sizeof(float), stream);
        k_deg<<<ge, 256, 0, stream>>>(ei, ew, deg, cnti, E);

        const int ns = N + 1;
        const int nb = (ns + 1023) / 1024;  // <=128
        k_scan1<<<nb, 256, 0, stream>>>(cnti, rowp, blks, ns);
        k_scan2<<<1, 128, 0, stream>>>(blks, nb);
        k_scan3<<<nb, 256, 0, stream>>>(rowp, blks, ns);

        k_dis<<<(N + 255) / 256, 256, 0, stream>>>(deg, cnti, dis, icn, N);
        k_scatter<<<ge, 256, 0, stream>>>(ei, ew, dis, rowp, fill, srcs, nrm, wts, E);

        k_gemm<<<gn, 256, 0, stream>>>(x, Wpre, bpre, h);
        k_gemm<<<gn, 256, 0, stream>>>(h, Wai, nullptr, t);

        k_pull<<<(N + 3) / 4, 256, 0, stream>>>(rowp, srcs, nrm, wts, t, h, agg, msg, N);
    } else {
        // fallback: push-scatter with atomics (zero agg,msg too)
        hipMemsetAsync(agg, 0, (2 * NF + (size_t)5 * N + 1) * sizeof(float), stream);
        k_deg<<<ge, 256, 0, stream>>>(ei, ew, deg, cnti, E);
        k_dis<<<(N + 255) / 256, 256, 0, stream>>>(deg, cnti, dis, icn, N);
        k_gemm<<<gn, 256, 0, stream>>>(x, Wpre, bpre, h);
        k_gemm<<<gn, 256, 0, stream>>>(h, Wai, nullptr, t);
        const long tot = (long)E * 128;
        k_edge<<<(int)((tot + 255) / 256), 256, 0, stream>>>(ei, ew, dis, t, h, agg, msg, E);
    }

    k_final_arma<<<gn, 256, 0, stream>>>(h, agg, War, ab, (float*)d_out);
    k_final_sage<<<gn, 256, 0, stream>>>(h, msg, icn, Wsl, Wsr, bsl, (float*)d_out);
}

// Round 3
// 846.514 us; speedup vs baseline: 2.4201x; 1.3009x over previous
//
#include <hip/hip_runtime.h>
#include <math.h>

// ---------------------------------------------------------------------------
// N=100000 nodes, E=1600000 edges, dims all 128.
// Round 3: exploit linearity (aggregate h, not t=h@Wai); 8-B edge records;
// CSR-derived degrees (no float atomics); on-the-fly norm in pull.
// ---------------------------------------------------------------------------

__device__ __forceinline__ float act_leaky_elu(float v) {
    float l = (v >= 0.0f) ? v : 0.01f * v;
    return (l > 0.0f) ? l : expm1f(l);
}

// in-edge count per target node
__global__ __launch_bounds__(256)
void k_cnt(const int* __restrict__ ei, int* __restrict__ cnti, int E) {
    int e = blockIdx.x * 256 + threadIdx.x;
    if (e < E) atomicAdd(&cnti[ei[E + e]], 1);
}

// ---- hierarchical exclusive scan over n ints ----
__global__ __launch_bounds__(256)
void k_scan1(const int* __restrict__ in, int* __restrict__ out,
             int* __restrict__ blksum, int n) {
    __shared__ int sh[256];
    const int tid = threadIdx.x;
    const int idx = blockIdx.x * 1024 + tid * 4;
    int v0 = (idx + 0 < n) ? in[idx + 0] : 0;
    int v1 = (idx + 1 < n) ? in[idx + 1] : 0;
    int v2 = (idx + 2 < n) ? in[idx + 2] : 0;
    int v3 = (idx + 3 < n) ? in[idx + 3] : 0;
    int tsum = v0 + v1 + v2 + v3;
    sh[tid] = tsum;
    __syncthreads();
    #pragma unroll
    for (int off = 1; off < 256; off <<= 1) {
        int add = (tid >= off) ? sh[tid - off] : 0;
        __syncthreads();
        sh[tid] += add;
        __syncthreads();
    }
    int excl = sh[tid] - tsum;
    if (idx + 0 < n) out[idx + 0] = excl;
    if (idx + 1 < n) out[idx + 1] = excl + v0;
    if (idx + 2 < n) out[idx + 2] = excl + v0 + v1;
    if (idx + 3 < n) out[idx + 3] = excl + v0 + v1 + v2;
    if (tid == 255) blksum[blockIdx.x] = sh[255];
}

__global__ __launch_bounds__(128)
void k_scan2(int* __restrict__ blksum, int nb) {
    __shared__ int sh[128];
    const int tid = threadIdx.x;
    int orig = (tid < nb) ? blksum[tid] : 0;
    sh[tid] = orig;
    __syncthreads();
    #pragma unroll
    for (int off = 1; off < 128; off <<= 1) {
        int add = (tid >= off) ? sh[tid - off] : 0;
        __syncthreads();
        sh[tid] += add;
        __syncthreads();
    }
    if (tid < nb) blksum[tid] = sh[tid] - orig;
}

__global__ __launch_bounds__(256)
void k_scan3(int* __restrict__ out, const int* __restrict__ blksum, int n) {
    const int add = blksum[blockIdx.x];
    const int base = blockIdx.x * 1024 + threadIdx.x;
    #pragma unroll
    for (int i = 0; i < 4; ++i) {
        int idx = base + i * 256;
        if (idx < n) out[idx] += add;
    }
}

// scatter edges into CSR slots as 8-B records {src, w}
__global__ __launch_bounds__(256)
void k_scatter(const int* __restrict__ ei, const float* __restrict__ ew,
               const int* __restrict__ rowp, int* __restrict__ fill,
               int2* __restrict__ recs, int E) {
    int e = blockIdx.x * 256 + threadIdx.x;
    if (e < E) {
        int r = ei[e];
        int c = ei[E + e];
        int pos = rowp[c] + atomicAdd(&fill[c], 1);
        recs[pos] = make_int2(r, __float_as_int(ew[e]));
    }
}

// per-node weighted degree from CSR (contiguous reads, no atomics) -> dis, icn
__global__ __launch_bounds__(256)
void k_degsum(const int* __restrict__ rowp, const int2* __restrict__ recs,
              float* __restrict__ dis, float* __restrict__ icn, int N) {
    int n = blockIdx.x * 256 + threadIdx.x;
    if (n >= N) return;
    int s = rowp[n], eE = rowp[n + 1];
    float d = 0.0f;
    for (int e = s; e < eE; ++e) d += __int_as_float(recs[e].y);
    dis[n] = (d > 0.0f) ? (1.0f / sqrtf(fmaxf(d, 1e-12f))) : 0.0f;
    icn[n] = 1.0f / fmaxf((float)(eE - s), 1.0f);
}

// Pull aggregation: one wave per node, 64 lanes x float2 = 128 features.
// aggH[n] = dis[n] * sum (dis[src]*w) * h[src] ; msg[n] = sum w * h[src]
__global__ __launch_bounds__(256)
void k_pull(const int* __restrict__ rowp, const int2* __restrict__ recs,
            const float* __restrict__ dis, const float* __restrict__ h,
            float* __restrict__ aggH, float* __restrict__ msg, int N) {
    const int node = blockIdx.x * 4 + (threadIdx.x >> 6);
    if (node >= N) return;
    const int lane = threadIdx.x & 63;
    int s  = __builtin_amdgcn_readfirstlane(rowp[node]);
    int eE = __builtin_amdgcn_readfirstlane(rowp[node + 1]);
    const float dcol = dis[node];
    float2 aA = make_float2(0.f, 0.f);
    float2 aM = make_float2(0.f, 0.f);
    int e = s;
    for (; e + 3 < eE; e += 4) {
        int2 r0 = recs[e], r1 = recs[e + 1], r2 = recs[e + 2], r3 = recs[e + 3];
        float d0 = dis[r0.x], d1 = dis[r1.x], d2 = dis[r2.x], d3 = dis[r3.x];
        float w0 = __int_as_float(r0.y), w1 = __int_as_float(r1.y);
        float w2 = __int_as_float(r2.y), w3 = __int_as_float(r3.y);
        float2 h0 = ((const float2*)(h + (size_t)r0.x * 128))[lane];
        float2 h1 = ((const float2*)(h + (size_t)r1.x * 128))[lane];
        float2 h2 = ((const float2*)(h + (size_t)r2.x * 128))[lane];
        float2 h3 = ((const float2*)(h + (size_t)r3.x * 128))[lane];
        float c0 = d0 * w0, c1 = d1 * w1, c2 = d2 * w2, c3 = d3 * w3;
        aA.x = fmaf(c0, h0.x, aA.x); aA.y = fmaf(c0, h0.y, aA.y);
        aM.x = fmaf(w0, h0.x, aM.x); aM.y = fmaf(w0, h0.y, aM.y);
        aA.x = fmaf(c1, h1.x, aA.x); aA.y = fmaf(c1, h1.y, aA.y);
        aM.x = fmaf(w1, h1.x, aM.x); aM.y = fmaf(w1, h1.y, aM.y);
        aA.x = fmaf(c2, h2.x, aA.x); aA.y = fmaf(c2, h2.y, aA.y);
        aM.x = fmaf(w2, h2.x, aM.x); aM.y = fmaf(w2, h2.y, aM.y);
        aA.x = fmaf(c3, h3.x, aA.x); aA.y = fmaf(c3, h3.y, aA.y);
        aM.x = fmaf(w3, h3.x, aM.x); aM.y = fmaf(w3, h3.y, aM.y);
    }
    for (; e < eE; ++e) {
        int2 r0 = recs[e];
        float d0 = dis[r0.x];
        float w0 = __int_as_float(r0.y);
        float2 h0 = ((const float2*)(h + (size_t)r0.x * 128))[lane];
        float c0 = d0 * w0;
        aA.x = fmaf(c0, h0.x, aA.x); aA.y = fmaf(c0, h0.y, aA.y);
        aM.x = fmaf(w0, h0.x, aM.x); aM.y = fmaf(w0, h0.y, aM.y);
    }
    aA.x *= dcol; aA.y *= dcol;
    ((float2*)(aggH + (size_t)node * 128))[lane] = aA;
    ((float2*)(msg + (size_t)node * 128))[lane] = aM;
}

// ---- fallback path kernels (ws too small for CSR) ----
__global__ __launch_bounds__(256)
void k_deg(const int* __restrict__ ei, const float* __restrict__ ew,
           float* __restrict__ deg, int* __restrict__ cnti, int E) {
    int e = blockIdx.x * 256 + threadIdx.x;
    if (e < E) {
        int c = ei[E + e];
        atomicAdd(&deg[c], ew[e]);
        atomicAdd(&cnti[c], 1);
    }
}

__global__ __launch_bounds__(256)
void k_dis(const float* __restrict__ deg, const int* __restrict__ cnti,
           float* __restrict__ dis, float* __restrict__ icn, int n) {
    int i = blockIdx.x * 256 + threadIdx.x;
    if (i < n) {
        float d = deg[i];
        dis[i] = (d > 0.0f) ? (1.0f / sqrtf(fmaxf(d, 1e-12f))) : 0.0f;
        icn[i] = 1.0f / fmaxf((float)cnti[i], 1.0f);
    }
}

__global__ __launch_bounds__(256)
void k_edge(const int* __restrict__ ei, const float* __restrict__ ew,
            const float* __restrict__ dis, const float* __restrict__ h,
            float* __restrict__ aggH, float* __restrict__ msg, int E) {
    unsigned tid = blockIdx.x * 256u + threadIdx.x;
    int e = tid >> 7;
    int f = tid & 127;
    if (e >= E) return;
    int r = ei[e];
    int c = ei[E + e];
    float wt = ew[e];
    float nr = dis[r] * wt * dis[c];
    float hv = h[(size_t)r * 128 + f];
    atomicAdd(&aggH[(size_t)c * 128 + f], nr * hv);
    atomicAdd(&msg[(size_t)c * 128 + f], wt * hv);
}

// C[n,128] = A[n,128] @ W[128,128] (+ bias). 32 rows/block, 4x4 reg tile.
__global__ __launch_bounds__(256)
void k_gemm(const float* __restrict__ A, const float* __restrict__ W,
            const float* __restrict__ bias, float* __restrict__ C) {
    __shared__ float Wl[128 * 128];
    for (int i = threadIdx.x; i < 4096; i += 256)
        ((float4*)Wl)[i] = ((const float4*)W)[i];
    __syncthreads();
    const int tx = threadIdx.x & 31;
    const int ty = threadIdx.x >> 5;
    const size_t row0 = (size_t)blockIdx.x * 32 + ty * 4;
    float4 bv = bias ? ((const float4*)bias)[tx] : make_float4(0.f, 0.f, 0.f, 0.f);
    float4 acc[4];
    acc[0] = bv; acc[1] = bv; acc[2] = bv; acc[3] = bv;
    const float* a = A + row0 * 128;
    #pragma unroll 4
    for (int k = 0; k < 128; ++k) {
        float4 wv = ((const float4*)(Wl + k * 128))[tx];
        #pragma unroll
        for (int i = 0; i < 4; ++i) {
            float av = a[i * 128 + k];
            acc[i].x = fmaf(av, wv.x, acc[i].x);
            acc[i].y = fmaf(av, wv.y, acc[i].y);
            acc[i].z = fmaf(av, wv.z, acc[i].z);
            acc[i].w = fmaf(av, wv.w, acc[i].w);
        }
    }
    #pragma unroll
    for (int i = 0; i < 4; ++i)
        ((float4*)(C + (row0 + i) * 128))[tx] = acc[i];
}

// out[:, 0:128] = relu( aggH @ Wai + h @ War + b )    (two LDS phases)
__global__ __launch_bounds__(256)
void k_final_arma(const float* __restrict__ h, const float* __restrict__ aggH,
                  const float* __restrict__ Wai, const float* __restrict__ War,
                  const float* __restrict__ b, float* __restrict__ out) {
    __shared__ float Wl[128 * 128];
    const int tx = threadIdx.x & 31;
    const int ty = threadIdx.x >> 5;
    const size_t row0 = (size_t)blockIdx.x * 32 + ty * 4;

    for (int i = threadIdx.x; i < 4096; i += 256)
        ((float4*)Wl)[i] = ((const float4*)Wai)[i];
    __syncthreads();
    float4 acc[4];
    acc[0] = acc[1] = acc[2] = acc[3] = make_float4(0.f, 0.f, 0.f, 0.f);
    {
        const float* m = aggH + row0 * 128;
        #pragma unroll 4
        for (int k = 0; k < 128; ++k) {
            float4 wv = ((const float4*)(Wl + k * 128))[tx];
            #pragma unroll
            for (int i = 0; i < 4; ++i) {
                float mv = m[i * 128 + k];
                acc[i].x = fmaf(mv, wv.x, acc[i].x);
                acc[i].y = fmaf(mv, wv.y, acc[i].y);
                acc[i].z = fmaf(mv, wv.z, acc[i].z);
                acc[i].w = fmaf(mv, wv.w, acc[i].w);
            }
        }
    }
    __syncthreads();
    for (int i = threadIdx.x; i < 4096; i += 256)
        ((float4*)Wl)[i] = ((const float4*)War)[i];
    __syncthreads();
    {
        const float* a = h + row0 * 128;
        #pragma unroll 4
        for (int k = 0; k < 128; ++k) {
            float4 wv = ((const float4*)(Wl + k * 128))[tx];
            #pragma unroll
            for (int i = 0; i < 4; ++i) {
                float av = a[i * 128 + k];
                acc[i].x = fmaf(av, wv.x, acc[i].x);
                acc[i].y = fmaf(av, wv.y, acc[i].y);
                acc[i].z = fmaf(av, wv.z, acc[i].z);
                acc[i].w = fmaf(av, wv.w, acc[i].w);
            }
        }
    }
    float4 bv = ((const float4*)b)[tx];
    #pragma unroll
    for (int i = 0; i < 4; ++i) {
        float4 v;
        v.x = fmaxf(acc[i].x + bv.x, 0.0f);
        v.y = fmaxf(acc[i].y + bv.y, 0.0f);
        v.z = fmaxf(acc[i].z + bv.z, 0.0f);
        v.w = fmaxf(acc[i].w + bv.w, 0.0f);
        ((float4*)(out + (row0 + i) * 256))[tx] = v;
    }
}

// out[:, 128:256] = elu(leaky( icn*(msg @ Wl) + h @ Wr + bl ))
__global__ __launch_bounds__(256)
void k_final_sage(const float* __restrict__ h, const float* __restrict__ msg,
                  const float* __restrict__ icn, const float* __restrict__ Wlw,
                  const float* __restrict__ Wrw, const float* __restrict__ bl,
                  float* __restrict__ out) {
    __shared__ float Wl[128 * 128];
    const int tx = threadIdx.x & 31;
    const int ty = threadIdx.x >> 5;
    const size_t row0 = (size_t)blockIdx.x * 32 + ty * 4;

    for (int i = threadIdx.x; i < 4096; i += 256)
        ((float4*)Wl)[i] = ((const float4*)Wlw)[i];
    __syncthreads();
    float4 acc[4];
    acc[0] = acc[1] = acc[2] = acc[3] = make_float4(0.f, 0.f, 0.f, 0.f);
    {
        const float* m = msg + row0 * 128;
        #pragma unroll 4
        for (int k = 0; k < 128; ++k) {
            float4 wv = ((const float4*)(Wl + k * 128))[tx];
            #pragma unroll
            for (int i = 0; i < 4; ++i) {
                float mv = m[i * 128 + k];
                acc[i].x = fmaf(mv, wv.x, acc[i].x);
                acc[i].y = fmaf(mv, wv.y, acc[i].y);
                acc[i].z = fmaf(mv, wv.z, acc[i].z);
                acc[i].w = fmaf(mv, wv.w, acc[i].w);
            }
        }
    }
    #pragma unroll
    for (int i = 0; i < 4; ++i) {
        float s = icn[row0 + i];
        acc[i].x *= s; acc[i].y *= s; acc[i].z *= s; acc[i].w *= s;
    }
    __syncthreads();
    for (int i = threadIdx.x; i < 4096; i += 256)
        ((float4*)Wl)[i] = ((const float4*)Wrw)[i];
    __syncthreads();
    {
        const float* a = h + row0 * 128;
        #pragma unroll 4
        for (int k = 0; k < 128; ++k) {
            float4 wv = ((const float4*)(Wl + k * 128))[tx];
            #pragma unroll
            for (int i = 0; i < 4; ++i) {
                float av = a[i * 128 + k];
                acc[i].x = fmaf(av, wv.x, acc[i].x);
                acc[i].y = fmaf(av, wv.y, acc[i].y);
                acc[i].z = fmaf(av, wv.z, acc[i].z);
                acc[i].w = fmaf(av, wv.w, acc[i].w);
            }
        }
    }
    float4 bv = ((const float4*)bl)[tx];
    #pragma unroll
    for (int i = 0; i < 4; ++i) {
        float4 v;
        v.x = act_leaky_elu(acc[i].x + bv.x);
        v.y = act_leaky_elu(acc[i].y + bv.y);
        v.z = act_leaky_elu(acc[i].z + bv.z);
        v.w = act_leaky_elu(acc[i].w + bv.w);
        ((float4*)(out + (row0 + i) * 256 + 128))[tx] = v;
    }
}

extern "C" void kernel_launch(void* const* d_in, const int* in_sizes, int n_in,
                              void* d_out, int out_size, void* d_ws, size_t ws_size,
                              hipStream_t stream) {
    const float* x    = (const float*)d_in[0];
    const int*   ei   = (const int*)d_in[1];
    const float* ew   = (const float*)d_in[2];
    const float* Wpre = (const float*)d_in[3];
    const float* bpre = (const float*)d_in[4];
    const float* Wai  = (const float*)d_in[5];
    const float* War  = (const float*)d_in[6];
    const float* ab   = (const float*)d_in[7];
    const float* Wsl  = (const float*)d_in[8];
    const float* bsl  = (const float*)d_in[9];
    const float* Wsr  = (const float*)d_in[10];

    const int N = in_sizes[0] / 128;
    const int E = in_sizes[2];
    const size_t NF = (size_t)N * 128;

    float* ws   = (float*)d_ws;
    float* h    = ws;                       // NF
    float* aggH = h + NF;                   // NF
    float* msg  = aggH + NF;                // NF
    float* dis  = msg + NF;                 // N
    float* icn  = dis + N;                  // N
    int*   cnti = (int*)(icn + N);          // N+1   (zeroed)
    int*   fill = cnti + (N + 1);           // N     (zeroed)
    int*   rowp = fill + N;                 // N+1
    int*   blks = rowp + (N + 1);           // 128
    int2*  recs = (int2*)(blks + 128);      // E int2

    const size_t need_csr = (size_t)((char*)(recs + E) - (char*)ws);
    const bool use_csr = ws_size >= need_csr;

    const int gn = (N + 31) / 32;
    const int ge = (E + 255) / 256;
    const int gv = (N + 255) / 256;

    if (use_csr) {
        hipMemsetAsync(cnti, 0, ((size_t)2 * N + 1) * sizeof(int), stream);
        k_cnt<<<ge, 256, 0, stream>>>(ei, cnti, E);

        const int ns = N + 1;
        const int nb = (ns + 1023) / 1024;
        k_scan1<<<nb, 256, 0, stream>>>(cnti, rowp, blks, ns);
        k_scan2<<<1, 128, 0, stream>>>(blks, nb);
        k_scan3<<<nb, 256, 0, stream>>>(rowp, blks, ns);

        k_scatter<<<ge, 256, 0, stream>>>(ei, ew, rowp, fill, recs, E);
        k_degsum<<<gv, 256, 0, stream>>>(rowp, recs, dis, icn, N);

        k_gemm<<<gn, 256, 0, stream>>>(x, Wpre, bpre, h);
        k_pull<<<(N + 3) / 4, 256, 0, stream>>>(rowp, recs, dis, h, aggH, msg, N);
    } else {
        float* deg = (float*)recs;          // reuse (fallback only)
        hipMemsetAsync(aggH, 0, 2 * NF * sizeof(float), stream);
        hipMemsetAsync(cnti, 0, (N + 1) * sizeof(int), stream);
        hipMemsetAsync(deg, 0, (size_t)N * sizeof(float), stream);
        k_deg<<<ge, 256, 0, stream>>>(ei, ew, deg, cnti, E);
        k_dis<<<gv, 256, 0, stream>>>(deg, cnti, dis, icn, N);
        k_gemm<<<gn, 256, 0, stream>>>(x, Wpre, bpre, h);
        const long tot = (long)E * 128;
        k_edge<<<(int)((tot + 255) / 256), 256, 0, stream>>>(ei, ew, dis, h, aggH, msg, E);
    }

    k_final_arma<<<gn, 256, 0, stream>>>(h, aggH, Wai, War, ab, (float*)d_out);
    k_final_sage<<<gn, 256, 0, stream>>>(h, msg, icn, Wsl, Wsr, bsl, (float*)d_out);
}

// Round 5
// 509.923 us; speedup vs baseline: 4.0176x; 1.6601x over previous
//
#include <hip/hip_runtime.h>
#include <math.h>

// ---------------------------------------------------------------------------
// N=100000, E=1600000, dims 128. Round 5 = Round 4 + fix: k_pull row stride
// is 64 uint32 (128 bf16), not 32. bf16 MFMA dense GEMMs (register-resident
// weight fragments, no LDS); bf16 h/agg/mean to halve pull gather traffic.
// ---------------------------------------------------------------------------

typedef __attribute__((ext_vector_type(8))) short short8;   // 8 bf16 (4 VGPR)
typedef __attribute__((ext_vector_type(4))) float float4v;  // 4 fp32 acc

__device__ __forceinline__ unsigned f2bf_pack(float a, float b) {
    unsigned ua = __float_as_uint(a);
    unsigned ub = __float_as_uint(b);
    ua += 0x7FFF + ((ua >> 16) & 1);   // RNE
    ub += 0x7FFF + ((ub >> 16) & 1);
    return (ua >> 16) | (ub & 0xFFFF0000u);
}

__device__ __forceinline__ unsigned short f2bf1(float a) {
    unsigned u = __float_as_uint(a);
    u += 0x7FFF + ((u >> 16) & 1);
    return (unsigned short)(u >> 16);
}

__device__ __forceinline__ float act_leaky_elu(float v) {
    float l = (v >= 0.0f) ? v : 0.01f * v;
    return (l > 0.0f) ? l : expm1f(l);
}

// B-fragment for mfma_16x16x32_bf16 from fp32 W[k][n] (row-major [128][128]):
// lane (q=lane>>4, n=lane&15) holds B[k0+j][n], j=0..7.
__device__ __forceinline__ short8 load_bfrag(const float* __restrict__ W,
                                             int n, int k0) {
    union { short8 s8; unsigned u[4]; } r;
    #pragma unroll
    for (int j = 0; j < 4; ++j) {
        float a = W[(k0 + 2 * j) * 128 + n];
        float b = W[(k0 + 2 * j + 1) * 128 + n];
        r.u[j] = f2bf_pack(a, b);
    }
    return r.s8;
}

// A-fragment from fp32 row pointer (8 consecutive floats -> 8 bf16)
__device__ __forceinline__ short8 load_afrag_f32(const float* __restrict__ p) {
    float4 a = ((const float4*)p)[0];
    float4 b = ((const float4*)p)[1];
    union { short8 s8; unsigned u[4]; } r;
    r.u[0] = f2bf_pack(a.x, a.y); r.u[1] = f2bf_pack(a.z, a.w);
    r.u[2] = f2bf_pack(b.x, b.y); r.u[3] = f2bf_pack(b.z, b.w);
    return r.s8;
}

// ---------------- CSR build ----------------
__global__ __launch_bounds__(256)
void k_cnt(const int* __restrict__ ei, int* __restrict__ cnti, int E) {
    int e = blockIdx.x * 256 + threadIdx.x;
    if (e < E) atomicAdd(&cnti[ei[E + e]], 1);
}

__global__ __launch_bounds__(256)
void k_scan1(const int* __restrict__ in, int* __restrict__ out,
             int* __restrict__ blksum, int n) {
    __shared__ int sh[256];
    const int tid = threadIdx.x;
    const int idx = blockIdx.x * 1024 + tid * 4;
    int v0 = (idx + 0 < n) ? in[idx + 0] : 0;
    int v1 = (idx + 1 < n) ? in[idx + 1] : 0;
    int v2 = (idx + 2 < n) ? in[idx + 2] : 0;
    int v3 = (idx + 3 < n) ? in[idx + 3] : 0;
    int tsum = v0 + v1 + v2 + v3;
    sh[tid] = tsum;
    __syncthreads();
    #pragma unroll
    for (int off = 1; off < 256; off <<= 1) {
        int add = (tid >= off) ? sh[tid - off] : 0;
        __syncthreads();
        sh[tid] += add;
        __syncthreads();
    }
    int excl = sh[tid] - tsum;
    if (idx + 0 < n) out[idx + 0] = excl;
    if (idx + 1 < n) out[idx + 1] = excl + v0;
    if (idx + 2 < n) out[idx + 2] = excl + v0 + v1;
    if (idx + 3 < n) out[idx + 3] = excl + v0 + v1 + v2;
    if (tid == 255) blksum[blockIdx.x] = sh[255];
}

__global__ __launch_bounds__(128)
void k_scan2(int* __restrict__ blksum, int nb) {
    __shared__ int sh[128];
    const int tid = threadIdx.x;
    int orig = (tid < nb) ? blksum[tid] : 0;
    sh[tid] = orig;
    __syncthreads();
    #pragma unroll
    for (int off = 1; off < 128; off <<= 1) {
        int add = (tid >= off) ? sh[tid - off] : 0;
        __syncthreads();
        sh[tid] += add;
        __syncthreads();
    }
    if (tid < nb) blksum[tid] = sh[tid] - orig;
}

__global__ __launch_bounds__(256)
void k_scan3(int* __restrict__ out, const int* __restrict__ blksum, int n) {
    const int add = blksum[blockIdx.x];
    const int base = blockIdx.x * 1024 + threadIdx.x;
    #pragma unroll
    for (int i = 0; i < 4; ++i) {
        int idx = base + i * 256;
        if (idx < n) out[idx] += add;
    }
}

__global__ __launch_bounds__(256)
void k_scatter(const int* __restrict__ ei, const float* __restrict__ ew,
               const int* __restrict__ rowp, int* __restrict__ fill,
               int2* __restrict__ recs, int E) {
    int e = blockIdx.x * 256 + threadIdx.x;
    if (e < E) {
        int r = ei[e];
        int c = ei[E + e];
        int pos = rowp[c] + atomicAdd(&fill[c], 1);
        recs[pos] = make_int2(r, __float_as_int(ew[e]));
    }
}

__global__ __launch_bounds__(256)
void k_degsum(const int* __restrict__ rowp, const int2* __restrict__ recs,
              float* __restrict__ dis, int N) {
    int n = blockIdx.x * 256 + threadIdx.x;
    if (n >= N) return;
    int s = rowp[n], eE = rowp[n + 1];
    float d = 0.0f;
    for (int e = s; e < eE; ++e) d += __int_as_float(recs[e].y);
    dis[n] = (d > 0.0f) ? (1.0f / sqrtf(fmaxf(d, 1e-12f))) : 0.0f;
}

// ---------------- preprocessor GEMM: hb = bf16(x @ Wpre + bpre) ----------------
__global__ __launch_bounds__(256)
void k_pre(const float* __restrict__ x, const float* __restrict__ Wpre,
           const float* __restrict__ bpre, unsigned short* __restrict__ hb,
           int N) {
    const int lane = threadIdx.x & 63;
    const int wv = threadIdx.x >> 6;
    const int q = lane >> 4;
    const int m = lane & 15;
    const int cg = wv * 32;
    short8 B[2][4];
    #pragma unroll
    for (int ct = 0; ct < 2; ++ct)
        #pragma unroll
        for (int c = 0; c < 4; ++c)
            B[ct][c] = load_bfrag(Wpre, cg + ct * 16 + m, c * 32 + q * 8);
    const float b0 = bpre[cg + m];
    const float b1 = bpre[cg + 16 + m];
    const int rb = blockIdx.x * 128;
    #pragma unroll 2
    for (int rt = 0; rt < 8; ++rt) {
        int row = rb + rt * 16 + m;
        int rc = min(row, N - 1);
        const float* xp = x + (size_t)rc * 128 + q * 8;
        float4v a0 = {0.f, 0.f, 0.f, 0.f}, a1 = {0.f, 0.f, 0.f, 0.f};
        #pragma unroll
        for (int c = 0; c < 4; ++c) {
            short8 a = load_afrag_f32(xp + c * 32);
            a0 = __builtin_amdgcn_mfma_f32_16x16x32_bf16(a, B[0][c], a0, 0, 0, 0);
            a1 = __builtin_amdgcn_mfma_f32_16x16x32_bf16(a, B[1][c], a1, 0, 0, 0);
        }
        #pragma unroll
        for (int r = 0; r < 4; ++r) {
            int ro = rb + rt * 16 + q * 4 + r;
            if (ro < N) {
                hb[(size_t)ro * 128 + cg + m]      = f2bf1(a0[r] + b0);
                hb[(size_t)ro * 128 + cg + 16 + m] = f2bf1(a1[r] + b1);
            }
        }
    }
}

// ---------------- pull aggregation (bf16 gathers, fp32 accumulate) -------------
// Row stride: 128 bf16 = 64 uint32. Lane handles one uint32 (2 features).
__global__ __launch_bounds__(256)
void k_pull(const int* __restrict__ rowp, const int2* __restrict__ recs,
            const float* __restrict__ dis, const unsigned* __restrict__ hb,
            unsigned* __restrict__ agb, unsigned* __restrict__ mnb, int N) {
    const int node = blockIdx.x * 4 + (threadIdx.x >> 6);
    if (node >= N) return;
    const int lane = threadIdx.x & 63;
    int s  = __builtin_amdgcn_readfirstlane(rowp[node]);
    int eE = __builtin_amdgcn_readfirstlane(rowp[node + 1]);
    const float dcol = dis[node];
    const float im = 1.0f / fmaxf((float)(eE - s), 1.0f);
    float2 aA = make_float2(0.f, 0.f);
    float2 aM = make_float2(0.f, 0.f);
    int e = s;
    for (; e + 3 < eE; e += 4) {
        int2 r0 = recs[e], r1 = recs[e + 1], r2 = recs[e + 2], r3 = recs[e + 3];
        float d0 = dis[r0.x], d1 = dis[r1.x], d2 = dis[r2.x], d3 = dis[r3.x];
        float w0 = __int_as_float(r0.y), w1 = __int_as_float(r1.y);
        float w2 = __int_as_float(r2.y), w3 = __int_as_float(r3.y);
        unsigned u0 = hb[(size_t)r0.x * 64 + lane];
        unsigned u1 = hb[(size_t)r1.x * 64 + lane];
        unsigned u2 = hb[(size_t)r2.x * 64 + lane];
        unsigned u3 = hb[(size_t)r3.x * 64 + lane];
        float c0 = d0 * w0, c1 = d1 * w1, c2 = d2 * w2, c3 = d3 * w3;
        float lx, hx;
        lx = __uint_as_float(u0 << 16); hx = __uint_as_float(u0 & 0xFFFF0000u);
        aA.x = fmaf(c0, lx, aA.x); aA.y = fmaf(c0, hx, aA.y);
        aM.x = fmaf(w0, lx, aM.x); aM.y = fmaf(w0, hx, aM.y);
        lx = __uint_as_float(u1 << 16); hx = __uint_as_float(u1 & 0xFFFF0000u);
        aA.x = fmaf(c1, lx, aA.x); aA.y = fmaf(c1, hx, aA.y);
        aM.x = fmaf(w1, lx, aM.x); aM.y = fmaf(w1, hx, aM.y);
        lx = __uint_as_float(u2 << 16); hx = __uint_as_float(u2 & 0xFFFF0000u);
        aA.x = fmaf(c2, lx, aA.x); aA.y = fmaf(c2, hx, aA.y);
        aM.x = fmaf(w2, lx, aM.x); aM.y = fmaf(w2, hx, aM.y);
        lx = __uint_as_float(u3 << 16); hx = __uint_as_float(u3 & 0xFFFF0000u);
        aA.x = fmaf(c3, lx, aA.x); aA.y = fmaf(c3, hx, aA.y);
        aM.x = fmaf(w3, lx, aM.x); aM.y = fmaf(w3, hx, aM.y);
    }
    for (; e < eE; ++e) {
        int2 r0 = recs[e];
        float d0 = dis[r0.x];
        float w0 = __int_as_float(r0.y);
        unsigned u0 = hb[(size_t)r0.x * 64 + lane];
        float c0 = d0 * w0;
        float lx = __uint_as_float(u0 << 16);
        float hx = __uint_as_float(u0 & 0xFFFF0000u);
        aA.x = fmaf(c0, lx, aA.x); aA.y = fmaf(c0, hx, aA.y);
        aM.x = fmaf(w0, lx, aM.x); aM.y = fmaf(w0, hx, aM.y);
    }
    agb[(size_t)node * 64 + lane] = f2bf_pack(aA.x * dcol, aA.y * dcol);
    mnb[(size_t)node * 64 + lane] = f2bf_pack(aM.x * im, aM.y * im);
}

// ---------------- fused epilogue: out = act(A1@W1 + A2@W2 + b) -----------------
// A1, A2 bf16 [N][128]; W fp32 [128][128]; out fp32 row stride 256 (pre-offset).
template <int ACT>
__global__ __launch_bounds__(256)
void k_final(const unsigned short* __restrict__ A1,
             const unsigned short* __restrict__ A2,
             const float* __restrict__ W1, const float* __restrict__ W2,
             const float* __restrict__ bias, float* __restrict__ out, int N) {
    const int lane = threadIdx.x & 63;
    const int wv = threadIdx.x >> 6;
    const int q = lane >> 4;
    const int m = lane & 15;
    const int cg = wv * 32;
    short8 B1[2][4], B2[2][4];
    #pragma unroll
    for (int ct = 0; ct < 2; ++ct)
        #pragma unroll
        for (int c = 0; c < 4; ++c) {
            B1[ct][c] = load_bfrag(W1, cg + ct * 16 + m, c * 32 + q * 8);
            B2[ct][c] = load_bfrag(W2, cg + ct * 16 + m, c * 32 + q * 8);
        }
    const float b0 = bias[cg + m];
    const float b1 = bias[cg + 16 + m];
    const int rb = blockIdx.x * 128;
    #pragma unroll 2
    for (int rt = 0; rt < 8; ++rt) {
        int row = rb + rt * 16 + m;
        int rc = min(row, N - 1);
        const short8* a1 = (const short8*)(A1 + (size_t)rc * 128 + q * 8);
        const short8* a2 = (const short8*)(A2 + (size_t)rc * 128 + q * 8);
        float4v c0 = {0.f, 0.f, 0.f, 0.f}, c1 = {0.f, 0.f, 0.f, 0.f};
        #pragma unroll
        for (int c = 0; c < 4; ++c) {
            short8 a = a1[c * 4];  // c*32 shorts
            c0 = __builtin_amdgcn_mfma_f32_16x16x32_bf16(a, B1[0][c], c0, 0, 0, 0);
            c1 = __builtin_amdgcn_mfma_f32_16x16x32_bf16(a, B1[1][c], c1, 0, 0, 0);
        }
        #pragma unroll
        for (int c = 0; c < 4; ++c) {
            short8 a = a2[c * 4];
            c0 = __builtin_amdgcn_mfma_f32_16x16x32_bf16(a, B2[0][c], c0, 0, 0, 0);
            c1 = __builtin_amdgcn_mfma_f32_16x16x32_bf16(a, B2[1][c], c1, 0, 0, 0);
        }
        #pragma unroll
        for (int r = 0; r < 4; ++r) {
            int ro = rb + rt * 16 + q * 4 + r;
            if (ro < N) {
                float v0 = c0[r] + b0;
                float v1 = c1[r] + b1;
                if (ACT == 0) { v0 = fmaxf(v0, 0.f); v1 = fmaxf(v1, 0.f); }
                else          { v0 = act_leaky_elu(v0); v1 = act_leaky_elu(v1); }
                out[(size_t)ro * 256 + cg + m]      = v0;
                out[(size_t)ro * 256 + cg + 16 + m] = v1;
            }
        }
    }
}

extern "C" void kernel_launch(void* const* d_in, const int* in_sizes, int n_in,
                              void* d_out, int out_size, void* d_ws, size_t ws_size,
                              hipStream_t stream) {
    const float* x    = (const float*)d_in[0];
    const int*   ei   = (const int*)d_in[1];
    const float* ew   = (const float*)d_in[2];
    const float* Wpre = (const float*)d_in[3];
    const float* bpre = (const float*)d_in[4];
    const float* Wai  = (const float*)d_in[5];
    const float* War  = (const float*)d_in[6];
    const float* ab   = (const float*)d_in[7];
    const float* Wsl  = (const float*)d_in[8];
    const float* bsl  = (const float*)d_in[9];
    const float* Wsr  = (const float*)d_in[10];

    const int N = in_sizes[0] / 128;
    const int E = in_sizes[2];
    const size_t NF = (size_t)N * 128;

    unsigned short* hb  = (unsigned short*)d_ws;  // NF bf16
    unsigned short* agb = hb + NF;                // NF bf16
    unsigned short* mnb = agb + NF;               // NF bf16
    float* dis  = (float*)(mnb + NF);             // N
    int*   cnti = (int*)(dis + N);                // N+1 (zeroed)
    int*   fill = cnti + (N + 1);                 // N   (zeroed)
    int*   rowp = fill + N;                       // N+1
    int*   blks = rowp + (N + 1);                 // 128
    int2*  recs = (int2*)(blks + 128);            // E

    const int ge = (E + 255) / 256;
    const int gv = (N + 255) / 256;
    const int gd = (N + 127) / 128;   // dense GEMM blocks (128 rows each)

    hipMemsetAsync(cnti, 0, ((size_t)2 * N + 1) * sizeof(int), stream);
    k_cnt<<<ge, 256, 0, stream>>>(ei, cnti, E);

    const int ns = N + 1;
    const int nb = (ns + 1023) / 1024;
    k_scan1<<<nb, 256, 0, stream>>>(cnti, rowp, blks, ns);
    k_scan2<<<1, 128, 0, stream>>>(blks, nb);
    k_scan3<<<nb, 256, 0, stream>>>(rowp, blks, ns);

    k_scatter<<<ge, 256, 0, stream>>>(ei, ew, rowp, fill, recs, E);
    k_degsum<<<gv, 256, 0, stream>>>(rowp, recs, dis, N);

    k_pre<<<gd, 256, 0, stream>>>(x, Wpre, bpre, hb, N);
    k_pull<<<(N + 3) / 4, 256, 0, stream>>>(rowp, recs, dis,
                                            (const unsigned*)hb,
                                            (unsigned*)agb, (unsigned*)mnb, N);

    float* out = (float*)d_out;
    k_final<0><<<gd, 256, 0, stream>>>(agb, hb, Wai, War, ab, out, N);
    k_final<1><<<gd, 256, 0, stream>>>(mnb, hb, Wsl, Wsr, bsl, out + 128, N);
}

// Round 6
// 489.020 us; speedup vs baseline: 4.1893x; 1.0427x over previous
//
#include <hip/hip_runtime.h>
#include <math.h>

// ---------------------------------------------------------------------------
// N=100000, E=1600000, dims 128. Round 6:
//  - rank trick: k_cnt stores each edge's intra-bucket rank -> atomic-free
//    scatter (one random 8-B store per edge, no RMW).
//  - k_pull: 2 edges per wave (half-wave = 32 lanes x uint2 = full 256-B row),
//    4 edges in flight; halves write agb/mnb respectively after shfl_xor(32).
// ---------------------------------------------------------------------------

typedef __attribute__((ext_vector_type(8))) short short8;   // 8 bf16 (4 VGPR)
typedef __attribute__((ext_vector_type(4))) float float4v;  // 4 fp32 acc

__device__ __forceinline__ unsigned f2bf_pack(float a, float b) {
    unsigned ua = __float_as_uint(a);
    unsigned ub = __float_as_uint(b);
    ua += 0x7FFF + ((ua >> 16) & 1);   // RNE
    ub += 0x7FFF + ((ub >> 16) & 1);
    return (ua >> 16) | (ub & 0xFFFF0000u);
}

__device__ __forceinline__ unsigned short f2bf1(float a) {
    unsigned u = __float_as_uint(a);
    u += 0x7FFF + ((u >> 16) & 1);
    return (unsigned short)(u >> 16);
}

__device__ __forceinline__ float act_leaky_elu(float v) {
    float l = (v >= 0.0f) ? v : 0.01f * v;
    return (l > 0.0f) ? l : expm1f(l);
}

// B-fragment for mfma_16x16x32_bf16 from fp32 W[k][n] (row-major [128][128]).
__device__ __forceinline__ short8 load_bfrag(const float* __restrict__ W,
                                             int n, int k0) {
    union { short8 s8; unsigned u[4]; } r;
    #pragma unroll
    for (int j = 0; j < 4; ++j) {
        float a = W[(k0 + 2 * j) * 128 + n];
        float b = W[(k0 + 2 * j + 1) * 128 + n];
        r.u[j] = f2bf_pack(a, b);
    }
    return r.s8;
}

__device__ __forceinline__ short8 load_afrag_f32(const float* __restrict__ p) {
    float4 a = ((const float4*)p)[0];
    float4 b = ((const float4*)p)[1];
    union { short8 s8; unsigned u[4]; } r;
    r.u[0] = f2bf_pack(a.x, a.y); r.u[1] = f2bf_pack(a.z, a.w);
    r.u[2] = f2bf_pack(b.x, b.y); r.u[3] = f2bf_pack(b.z, b.w);
    return r.s8;
}

// ---------------- CSR build ----------------
// count + rank: rank[e] = old count of target bucket
__global__ __launch_bounds__(256)
void k_cnt(const int* __restrict__ ei, int* __restrict__ cnti,
           int* __restrict__ rank, int E) {
    int e = blockIdx.x * 256 + threadIdx.x;
    if (e < E) rank[e] = atomicAdd(&cnti[ei[E + e]], 1);
}

__global__ __launch_bounds__(256)
void k_scan1(const int* __restrict__ in, int* __restrict__ out,
             int* __restrict__ blksum, int n) {
    __shared__ int sh[256];
    const int tid = threadIdx.x;
    const int idx = blockIdx.x * 1024 + tid * 4;
    int v0 = (idx + 0 < n) ? in[idx + 0] : 0;
    int v1 = (idx + 1 < n) ? in[idx + 1] : 0;
    int v2 = (idx + 2 < n) ? in[idx + 2] : 0;
    int v3 = (idx + 3 < n) ? in[idx + 3] : 0;
    int tsum = v0 + v1 + v2 + v3;
    sh[tid] = tsum;
    __syncthreads();
    #pragma unroll
    for (int off = 1; off < 256; off <<= 1) {
        int add = (tid >= off) ? sh[tid - off] : 0;
        __syncthreads();
        sh[tid] += add;
        __syncthreads();
    }
    int excl = sh[tid] - tsum;
    if (idx + 0 < n) out[idx + 0] = excl;
    if (idx + 1 < n) out[idx + 1] = excl + v0;
    if (idx + 2 < n) out[idx + 2] = excl + v0 + v1;
    if (idx + 3 < n) out[idx + 3] = excl + v0 + v1 + v2;
    if (tid == 255) blksum[blockIdx.x] = sh[255];
}

__global__ __launch_bounds__(128)
void k_scan2(int* __restrict__ blksum, int nb) {
    __shared__ int sh[128];
    const int tid = threadIdx.x;
    int orig = (tid < nb) ? blksum[tid] : 0;
    sh[tid] = orig;
    __syncthreads();
    #pragma unroll
    for (int off = 1; off < 128; off <<= 1) {
        int add = (tid >= off) ? sh[tid - off] : 0;
        __syncthreads();
        sh[tid] += add;
        __syncthreads();
    }
    if (tid < nb) blksum[tid] = sh[tid] - orig;
}

__global__ __launch_bounds__(256)
void k_scan3(int* __restrict__ out, const int* __restrict__ blksum, int n) {
    const int add = blksum[blockIdx.x];
    const int base = blockIdx.x * 1024 + threadIdx.x;
    #pragma unroll
    for (int i = 0; i < 4; ++i) {
        int idx = base + i * 256;
        if (idx < n) out[idx] += add;
    }
}

// atomic-free scatter: pos = rowp[c] + rank[e]
__global__ __launch_bounds__(256)
void k_scatter(const int* __restrict__ ei, const float* __restrict__ ew,
               const int* __restrict__ rowp, const int* __restrict__ rank,
               int2* __restrict__ recs, int E) {
    int e = blockIdx.x * 256 + threadIdx.x;
    if (e < E) {
        int c = ei[E + e];
        int pos = rowp[c] + rank[e];
        recs[pos] = make_int2(ei[e], __float_as_int(ew[e]));
    }
}

__global__ __launch_bounds__(256)
void k_degsum(const int* __restrict__ rowp, const int2* __restrict__ recs,
              float* __restrict__ dis, int N) {
    int n = blockIdx.x * 256 + threadIdx.x;
    if (n >= N) return;
    int s = rowp[n], eE = rowp[n + 1];
    float d = 0.0f;
    for (int e = s; e < eE; ++e) d += __int_as_float(recs[e].y);
    dis[n] = (d > 0.0f) ? (1.0f / sqrtf(fmaxf(d, 1e-12f))) : 0.0f;
}

// ---------------- preprocessor GEMM: hb = bf16(x @ Wpre + bpre) ----------------
__global__ __launch_bounds__(256)
void k_pre(const float* __restrict__ x, const float* __restrict__ Wpre,
           const float* __restrict__ bpre, unsigned short* __restrict__ hb,
           int N) {
    const int lane = threadIdx.x & 63;
    const int wv = threadIdx.x >> 6;
    const int q = lane >> 4;
    const int m = lane & 15;
    const int cg = wv * 32;
    short8 B[2][4];
    #pragma unroll
    for (int ct = 0; ct < 2; ++ct)
        #pragma unroll
        for (int c = 0; c < 4; ++c)
            B[ct][c] = load_bfrag(Wpre, cg + ct * 16 + m, c * 32 + q * 8);
    const float b0 = bpre[cg + m];
    const float b1 = bpre[cg + 16 + m];
    const int rb = blockIdx.x * 128;
    #pragma unroll 2
    for (int rt = 0; rt < 8; ++rt) {
        int row = rb + rt * 16 + m;
        int rc = min(row, N - 1);
        const float* xp = x + (size_t)rc * 128 + q * 8;
        float4v a0 = {0.f, 0.f, 0.f, 0.f}, a1 = {0.f, 0.f, 0.f, 0.f};
        #pragma unroll
        for (int c = 0; c < 4; ++c) {
            short8 a = load_afrag_f32(xp + c * 32);
            a0 = __builtin_amdgcn_mfma_f32_16x16x32_bf16(a, B[0][c], a0, 0, 0, 0);
            a1 = __builtin_amdgcn_mfma_f32_16x16x32_bf16(a, B[1][c], a1, 0, 0, 0);
        }
        #pragma unroll
        for (int r = 0; r < 4; ++r) {
            int ro = rb + rt * 16 + q * 4 + r;
            if (ro < N) {
                hb[(size_t)ro * 128 + cg + m]      = f2bf1(a0[r] + b0);
                hb[(size_t)ro * 128 + cg + 16 + m] = f2bf1(a1[r] + b1);
            }
        }
    }
}

// ---------------- pull aggregation: 2 edges per wave -----------------
// Half-wave (32 lanes x uint2 = 256 B) covers one full bf16 row.
// half 0 writes agb row, half 1 writes mnb row (sums identical post-shfl).
__global__ __launch_bounds__(256)
void k_pull(const int* __restrict__ rowp, const int2* __restrict__ recs,
            const float* __restrict__ dis, const unsigned* __restrict__ hb,
            unsigned* __restrict__ agb, unsigned* __restrict__ mnb, int N) {
    const int node = blockIdx.x * 4 + (threadIdx.x >> 6);
    if (node >= N) return;
    const int lane = threadIdx.x & 63;
    const int half = lane >> 5;          // 0 or 1: which edge of the pair
    const int sub = lane & 31;           // uint2 index within row (features 4*sub..+3)
    int s  = __builtin_amdgcn_readfirstlane(rowp[node]);
    int eE = __builtin_amdgcn_readfirstlane(rowp[node + 1]);
    const float dcol = dis[node];
    const float im = 1.0f / fmaxf((float)(eE - s), 1.0f);

    float aA0 = 0.f, aA1 = 0.f, aA2 = 0.f, aA3 = 0.f;
    float aM0 = 0.f, aM1 = 0.f, aM2 = 0.f, aM3 = 0.f;

    int e = s;
    for (; e + 3 < eE; e += 4) {
        int el0 = e + half, el1 = e + 2 + half;
        int2 r0 = recs[el0];
        int2 r1 = recs[el1];
        float d0 = dis[r0.x], d1 = dis[r1.x];
        float w0 = __int_as_float(r0.y), w1 = __int_as_float(r1.y);
        uint2 u0 = ((const uint2*)(hb + (size_t)r0.x * 64))[sub];
        uint2 u1 = ((const uint2*)(hb + (size_t)r1.x * 64))[sub];
        float c0 = d0 * w0, c1 = d1 * w1;
        float f0 = __uint_as_float(u0.x << 16);
        float f1 = __uint_as_float(u0.x & 0xFFFF0000u);
        float f2 = __uint_as_float(u0.y << 16);
        float f3 = __uint_as_float(u0.y & 0xFFFF0000u);
        aA0 = fmaf(c0, f0, aA0); aA1 = fmaf(c0, f1, aA1);
        aA2 = fmaf(c0, f2, aA2); aA3 = fmaf(c0, f3, aA3);
        aM0 = fmaf(w0, f0, aM0); aM1 = fmaf(w0, f1, aM1);
        aM2 = fmaf(w0, f2, aM2); aM3 = fmaf(w0, f3, aM3);
        f0 = __uint_as_float(u1.x << 16);
        f1 = __uint_as_float(u1.x & 0xFFFF0000u);
        f2 = __uint_as_float(u1.y << 16);
        f3 = __uint_as_float(u1.y & 0xFFFF0000u);
        aA0 = fmaf(c1, f0, aA0); aA1 = fmaf(c1, f1, aA1);
        aA2 = fmaf(c1, f2, aA2); aA3 = fmaf(c1, f3, aA3);
        aM0 = fmaf(w1, f0, aM0); aM1 = fmaf(w1, f1, aM1);
        aM2 = fmaf(w1, f2, aM2); aM3 = fmaf(w1, f3, aM3);
    }
    for (; e < eE; e += 2) {
        int el = e + half;
        if (el < eE) {
            int2 r0 = recs[el];
            float d0 = dis[r0.x];
            float w0 = __int_as_float(r0.y);
            uint2 u0 = ((const uint2*)(hb + (size_t)r0.x * 64))[sub];
            float c0 = d0 * w0;
            float f0 = __uint_as_float(u0.x << 16);
            float f1 = __uint_as_float(u0.x & 0xFFFF0000u);
            float f2 = __uint_as_float(u0.y << 16);
            float f3 = __uint_as_float(u0.y & 0xFFFF0000u);
            aA0 = fmaf(c0, f0, aA0); aA1 = fmaf(c0, f1, aA1);
            aA2 = fmaf(c0, f2, aA2); aA3 = fmaf(c0, f3, aA3);
            aM0 = fmaf(w0, f0, aM0); aM1 = fmaf(w0, f1, aM1);
            aM2 = fmaf(w0, f2, aM2); aM3 = fmaf(w0, f3, aM3);
        }
    }
    // combine the two halves
    aA0 += __shfl_xor(aA0, 32, 64); aA1 += __shfl_xor(aA1, 32, 64);
    aA2 += __shfl_xor(aA2, 32, 64); aA3 += __shfl_xor(aA3, 32, 64);
    aM0 += __shfl_xor(aM0, 32, 64); aM1 += __shfl_xor(aM1, 32, 64);
    aM2 += __shfl_xor(aM2, 32, 64); aM3 += __shfl_xor(aM3, 32, 64);

    if (half == 0) {
        uint2 o;
        o.x = f2bf_pack(aA0 * dcol, aA1 * dcol);
        o.y = f2bf_pack(aA2 * dcol, aA3 * dcol);
        ((uint2*)(agb + (size_t)node * 64))[sub] = o;
    } else {
        uint2 o;
        o.x = f2bf_pack(aM0 * im, aM1 * im);
        o.y = f2bf_pack(aM2 * im, aM3 * im);
        ((uint2*)(mnb + (size_t)node * 64))[sub] = o;
    }
}

// ---------------- fused epilogue: out = act(A1@W1 + A2@W2 + b) -----------------
template <int ACT>
__global__ __launch_bounds__(256)
void k_final(const unsigned short* __restrict__ A1,
             const unsigned short* __restrict__ A2,
             const float* __restrict__ W1, const float* __restrict__ W2,
             const float* __restrict__ bias, float* __restrict__ out, int N) {
    const int lane = threadIdx.x & 63;
    const int wv = threadIdx.x >> 6;
    const int q = lane >> 4;
    const int m = lane & 15;
    const int cg = wv * 32;
    short8 B1[2][4], B2[2][4];
    #pragma unroll
    for (int ct = 0; ct < 2; ++ct)
        #pragma unroll
        for (int c = 0; c < 4; ++c) {
            B1[ct][c] = load_bfrag(W1, cg + ct * 16 + m, c * 32 + q * 8);
            B2[ct][c] = load_bfrag(W2, cg + ct * 16 + m, c * 32 + q * 8);
        }
    const float b0 = bias[cg + m];
    const float b1 = bias[cg + 16 + m];
    const int rb = blockIdx.x * 128;
    #pragma unroll 2
    for (int rt = 0; rt < 8; ++rt) {
        int row = rb + rt * 16 + m;
        int rc = min(row, N - 1);
        const short8* a1 = (const short8*)(A1 + (size_t)rc * 128 + q * 8);
        const short8* a2 = (const short8*)(A2 + (size_t)rc * 128 + q * 8);
        float4v c0 = {0.f, 0.f, 0.f, 0.f}, c1 = {0.f, 0.f, 0.f, 0.f};
        #pragma unroll
        for (int c = 0; c < 4; ++c) {
            short8 a = a1[c * 4];
            c0 = __builtin_amdgcn_mfma_f32_16x16x32_bf16(a, B1[0][c], c0, 0, 0, 0);
            c1 = __builtin_amdgcn_mfma_f32_16x16x32_bf16(a, B1[1][c], c1, 0, 0, 0);
        }
        #pragma unroll
        for (int c = 0; c < 4; ++c) {
            short8 a = a2[c * 4];
            c0 = __builtin_amdgcn_mfma_f32_16x16x32_bf16(a, B2[0][c], c0, 0, 0, 0);
            c1 = __builtin_amdgcn_mfma_f32_16x16x32_bf16(a, B2[1][c], c1, 0, 0, 0);
        }
        #pragma unroll
        for (int r = 0; r < 4; ++r) {
            int ro = rb + rt * 16 + q * 4 + r;
            if (ro < N) {
                float v0 = c0[r] + b0;
                float v1 = c1[r] + b1;
                if (ACT == 0) { v0 = fmaxf(v0, 0.f); v1 = fmaxf(v1, 0.f); }
                else          { v0 = act_leaky_elu(v0); v1 = act_leaky_elu(v1); }
                out[(size_t)ro * 256 + cg + m]      = v0;
                out[(size_t)ro * 256 + cg + 16 + m] = v1;
            }
        }
    }
}

extern "C" void kernel_launch(void* const* d_in, const int* in_sizes, int n_in,
                              void* d_out, int out_size, void* d_ws, size_t ws_size,
                              hipStream_t stream) {
    const float* x    = (const float*)d_in[0];
    const int*   ei   = (const int*)d_in[1];
    const float* ew   = (const float*)d_in[2];
    const float* Wpre = (const float*)d_in[3];
    const float* bpre = (const float*)d_in[4];
    const float* Wai  = (const float*)d_in[5];
    const float* War  = (const float*)d_in[6];
    const float* ab   = (const float*)d_in[7];
    const float* Wsl  = (const float*)d_in[8];
    const float* bsl  = (const float*)d_in[9];
    const float* Wsr  = (const float*)d_in[10];

    const int N = in_sizes[0] / 128;
    const int E = in_sizes[2];
    const size_t NF = (size_t)N * 128;

    unsigned short* hb  = (unsigned short*)d_ws;  // NF bf16
    unsigned short* agb = hb + NF;                // NF bf16
    unsigned short* mnb = agb + NF;               // NF bf16
    float* dis  = (float*)(mnb + NF);             // N
    int*   cnti = (int*)(dis + N);                // N+1 (zeroed)
    int*   rowp = cnti + (N + 1);                 // N+1
    int*   blks = rowp + (N + 1);                 // 128
    int*   rank = blks + 128;                     // E
    int2*  recs = (int2*)(rank + E);              // E

    const int ge = (E + 255) / 256;
    const int gv = (N + 255) / 256;
    const int gd = (N + 127) / 128;

    hipMemsetAsync(cnti, 0, (N + 1) * sizeof(int), stream);
    k_cnt<<<ge, 256, 0, stream>>>(ei, cnti, rank, E);

    const int ns = N + 1;
    const int nb = (ns + 1023) / 1024;
    k_scan1<<<nb, 256, 0, stream>>>(cnti, rowp, blks, ns);
    k_scan2<<<1, 128, 0, stream>>>(blks, nb);
    k_scan3<<<nb, 256, 0, stream>>>(rowp, blks, ns);

    k_scatter<<<ge, 256, 0, stream>>>(ei, ew, rowp, rank, recs, E);
    k_degsum<<<gv, 256, 0, stream>>>(rowp, recs, dis, N);

    k_pre<<<gd, 256, 0, stream>>>(x, Wpre, bpre, hb, N);
    k_pull<<<(N + 3) / 4, 256, 0, stream>>>(rowp, recs, dis,
                                            (const unsigned*)hb,
                                            (unsigned*)agb, (unsigned*)mnb, N);

    float* out = (float*)d_out;
    k_final<0><<<gd, 256, 0, stream>>>(agb, hb, Wai, War, ab, out, N);
    k_final<1><<<gd, 256, 0, stream>>>(mnb, hb, Wsl, Wsr, bsl, out + 128, N);
}

// Round 7
// 457.487 us; speedup vs baseline: 4.4781x; 1.0689x over previous
//
#include <hip/hip_runtime.h>
#include <math.h>

// ---------------------------------------------------------------------------
// N=100000, E=1600000, dims 128. Round 7:
//  - k_pull: quarter-wave uint4 gathers (16 lanes x 16 B = full 256-B bf16 row,
//    4 edges per wave-iteration), fp32 accum, shfl_xor(32/16) reduce.
//  - 4-B packed edge records: src in 17 bits, w as 15-bit fixed point
//    (halves scatter write-bounce + recs fetch). int2 fallback if N > 2^17.
// ---------------------------------------------------------------------------

typedef __attribute__((ext_vector_type(8))) short short8;   // 8 bf16 (4 VGPR)
typedef __attribute__((ext_vector_type(4))) float float4v;  // 4 fp32 acc

#define WQ_SCALE 32767.0f
#define WQ_INV   (1.0f / 32767.0f)

__device__ __forceinline__ unsigned f2bf_pack(float a, float b) {
    unsigned ua = __float_as_uint(a);
    unsigned ub = __float_as_uint(b);
    ua += 0x7FFF + ((ua >> 16) & 1);   // RNE
    ub += 0x7FFF + ((ub >> 16) & 1);
    return (ua >> 16) | (ub & 0xFFFF0000u);
}

__device__ __forceinline__ unsigned short f2bf1(float a) {
    unsigned u = __float_as_uint(a);
    u += 0x7FFF + ((u >> 16) & 1);
    return (unsigned short)(u >> 16);
}

__device__ __forceinline__ float act_leaky_elu(float v) {
    float l = (v >= 0.0f) ? v : 0.01f * v;
    return (l > 0.0f) ? l : expm1f(l);
}

// B-fragment for mfma_16x16x32_bf16 from fp32 W[k][n] (row-major [128][128]).
__device__ __forceinline__ short8 load_bfrag(const float* __restrict__ W,
                                             int n, int k0) {
    union { short8 s8; unsigned u[4]; } r;
    #pragma unroll
    for (int j = 0; j < 4; ++j) {
        float a = W[(k0 + 2 * j) * 128 + n];
        float b = W[(k0 + 2 * j + 1) * 128 + n];
        r.u[j] = f2bf_pack(a, b);
    }
    return r.s8;
}

__device__ __forceinline__ short8 load_afrag_f32(const float* __restrict__ p) {
    float4 a = ((const float4*)p)[0];
    float4 b = ((const float4*)p)[1];
    union { short8 s8; unsigned u[4]; } r;
    r.u[0] = f2bf_pack(a.x, a.y); r.u[1] = f2bf_pack(a.z, a.w);
    r.u[2] = f2bf_pack(b.x, b.y); r.u[3] = f2bf_pack(b.z, b.w);
    return r.s8;
}

// ---------------- CSR build ----------------
__global__ __launch_bounds__(256)
void k_cnt(const int* __restrict__ ei, int* __restrict__ cnti,
           int* __restrict__ rank, int E) {
    int e = blockIdx.x * 256 + threadIdx.x;
    if (e < E) rank[e] = atomicAdd(&cnti[ei[E + e]], 1);
}

__global__ __launch_bounds__(256)
void k_scan1(const int* __restrict__ in, int* __restrict__ out,
             int* __restrict__ blksum, int n) {
    __shared__ int sh[256];
    const int tid = threadIdx.x;
    const int idx = blockIdx.x * 1024 + tid * 4;
    int v0 = (idx + 0 < n) ? in[idx + 0] : 0;
    int v1 = (idx + 1 < n) ? in[idx + 1] : 0;
    int v2 = (idx + 2 < n) ? in[idx + 2] : 0;
    int v3 = (idx + 3 < n) ? in[idx + 3] : 0;
    int tsum = v0 + v1 + v2 + v3;
    sh[tid] = tsum;
    __syncthreads();
    #pragma unroll
    for (int off = 1; off < 256; off <<= 1) {
        int add = (tid >= off) ? sh[tid - off] : 0;
        __syncthreads();
        sh[tid] += add;
        __syncthreads();
    }
    int excl = sh[tid] - tsum;
    if (idx + 0 < n) out[idx + 0] = excl;
    if (idx + 1 < n) out[idx + 1] = excl + v0;
    if (idx + 2 < n) out[idx + 2] = excl + v0 + v1;
    if (idx + 3 < n) out[idx + 3] = excl + v0 + v1 + v2;
    if (tid == 255) blksum[blockIdx.x] = sh[255];
}

__global__ __launch_bounds__(128)
void k_scan2(int* __restrict__ blksum, int nb) {
    __shared__ int sh[128];
    const int tid = threadIdx.x;
    int orig = (tid < nb) ? blksum[tid] : 0;
    sh[tid] = orig;
    __syncthreads();
    #pragma unroll
    for (int off = 1; off < 128; off <<= 1) {
        int add = (tid >= off) ? sh[tid - off] : 0;
        __syncthreads();
        sh[tid] += add;
        __syncthreads();
    }
    if (tid < nb) blksum[tid] = sh[tid] - orig;
}

__global__ __launch_bounds__(256)
void k_scan3(int* __restrict__ out, const int* __restrict__ blksum, int n) {
    const int add = blksum[blockIdx.x];
    const int base = blockIdx.x * 1024 + threadIdx.x;
    #pragma unroll
    for (int i = 0; i < 4; ++i) {
        int idx = base + i * 256;
        if (idx < n) out[idx] += add;
    }
}

// packed scatter: one random 4-B store per edge
__global__ __launch_bounds__(256)
void k_scatterP(const int* __restrict__ ei, const float* __restrict__ ew,
                const int* __restrict__ rowp, const int* __restrict__ rank,
                unsigned* __restrict__ recs, int E) {
    int e = blockIdx.x * 256 + threadIdx.x;
    if (e < E) {
        int c = ei[E + e];
        int pos = rowp[c] + rank[e];
        unsigned wq = (unsigned)__builtin_rintf(ew[e] * WQ_SCALE);
        recs[pos] = (wq << 17) | (unsigned)ei[e];
    }
}

// wide fallback (N > 2^17)
__global__ __launch_bounds__(256)
void k_scatterW(const int* __restrict__ ei, const float* __restrict__ ew,
                const int* __restrict__ rowp, const int* __restrict__ rank,
                int2* __restrict__ recs, int E) {
    int e = blockIdx.x * 256 + threadIdx.x;
    if (e < E) {
        int c = ei[E + e];
        int pos = rowp[c] + rank[e];
        recs[pos] = make_int2(ei[e], __float_as_int(ew[e]));
    }
}

template <bool PACKED>
__global__ __launch_bounds__(256)
void k_degsum(const int* __restrict__ rowp, const void* __restrict__ recs_,
              float* __restrict__ dis, int N) {
    int n = blockIdx.x * 256 + threadIdx.x;
    if (n >= N) return;
    int s = rowp[n], eE = rowp[n + 1];
    float d = 0.0f;
    if (PACKED) {
        const unsigned* recs = (const unsigned*)recs_;
        for (int e = s; e < eE; ++e) d += (float)(recs[e] >> 17) * WQ_INV;
    } else {
        const int2* recs = (const int2*)recs_;
        for (int e = s; e < eE; ++e) d += __int_as_float(recs[e].y);
    }
    dis[n] = (d > 0.0f) ? (1.0f / sqrtf(fmaxf(d, 1e-12f))) : 0.0f;
}

// ---------------- preprocessor GEMM: hb = bf16(x @ Wpre + bpre) ----------------
__global__ __launch_bounds__(256)
void k_pre(const float* __restrict__ x, const float* __restrict__ Wpre,
           const float* __restrict__ bpre, unsigned short* __restrict__ hb,
           int N) {
    const int lane = threadIdx.x & 63;
    const int wv = threadIdx.x >> 6;
    const int q = lane >> 4;
    const int m = lane & 15;
    const int cg = wv * 32;
    short8 B[2][4];
    #pragma unroll
    for (int ct = 0; ct < 2; ++ct)
        #pragma unroll
        for (int c = 0; c < 4; ++c)
            B[ct][c] = load_bfrag(Wpre, cg + ct * 16 + m, c * 32 + q * 8);
    const float b0 = bpre[cg + m];
    const float b1 = bpre[cg + 16 + m];
    const int rb = blockIdx.x * 128;
    #pragma unroll 2
    for (int rt = 0; rt < 8; ++rt) {
        int row = rb + rt * 16 + m;
        int rc = min(row, N - 1);
        const float* xp = x + (size_t)rc * 128 + q * 8;
        float4v a0 = {0.f, 0.f, 0.f, 0.f}, a1 = {0.f, 0.f, 0.f, 0.f};
        #pragma unroll
        for (int c = 0; c < 4; ++c) {
            short8 a = load_afrag_f32(xp + c * 32);
            a0 = __builtin_amdgcn_mfma_f32_16x16x32_bf16(a, B[0][c], a0, 0, 0, 0);
            a1 = __builtin_amdgcn_mfma_f32_16x16x32_bf16(a, B[1][c], a1, 0, 0, 0);
        }
        #pragma unroll
        for (int r = 0; r < 4; ++r) {
            int ro = rb + rt * 16 + q * 4 + r;
            if (ro < N) {
                hb[(size_t)ro * 128 + cg + m]      = f2bf1(a0[r] + b0);
                hb[(size_t)ro * 128 + cg + 16 + m] = f2bf1(a1[r] + b1);
            }
        }
    }
}

// ---------------- pull aggregation: quarter-wave rows, 4 edges/iter -----------
// Quarter q handles edge e+q; 16 lanes x uint4 = full 256-B bf16 row.
template <bool PACKED>
__global__ __launch_bounds__(256)
void k_pull(const int* __restrict__ rowp, const void* __restrict__ recs_,
            const float* __restrict__ dis, const uint4* __restrict__ hb4,
            uint4* __restrict__ agb4, uint4* __restrict__ mnb4, int N) {
    const int node = blockIdx.x * 4 + (threadIdx.x >> 6);
    if (node >= N) return;
    const int lane = threadIdx.x & 63;
    const int q4 = lane >> 4;          // quarter: which edge of the group of 4
    const int sub = lane & 15;         // uint4 index within the 16-uint4 row
    int s  = __builtin_amdgcn_readfirstlane(rowp[node]);
    int eE = __builtin_amdgcn_readfirstlane(rowp[node + 1]);
    const float dcol = dis[node];
    const float im = 1.0f / fmaxf((float)(eE - s), 1.0f);

    float aA[8], aM[8];
    #pragma unroll
    for (int i = 0; i < 8; ++i) { aA[i] = 0.f; aM[i] = 0.f; }

    #pragma unroll 2
    for (int e = s; e < eE; e += 4) {
        int el = e + q4;
        bool ok = el < eE;
        int el2 = ok ? el : (eE - 1);
        int src; float w;
        if (PACKED) {
            unsigned rv = ((const unsigned*)recs_)[el2];
            src = (int)(rv & 0x1FFFFu);
            w = (float)(rv >> 17) * WQ_INV;
        } else {
            int2 rv = ((const int2*)recs_)[el2];
            src = rv.x;
            w = __int_as_float(rv.y);
        }
        if (!ok) w = 0.f;
        float c = dis[src] * w;
        uint4 u = hb4[(size_t)src * 16 + sub];
        float f0 = __uint_as_float(u.x << 16);
        float f1 = __uint_as_float(u.x & 0xFFFF0000u);
        float f2 = __uint_as_float(u.y << 16);
        float f3 = __uint_as_float(u.y & 0xFFFF0000u);
        float f4 = __uint_as_float(u.z << 16);
        float f5 = __uint_as_float(u.z & 0xFFFF0000u);
        float f6 = __uint_as_float(u.w << 16);
        float f7 = __uint_as_float(u.w & 0xFFFF0000u);
        aA[0] = fmaf(c, f0, aA[0]); aM[0] = fmaf(w, f0, aM[0]);
        aA[1] = fmaf(c, f1, aA[1]); aM[1] = fmaf(w, f1, aM[1]);
        aA[2] = fmaf(c, f2, aA[2]); aM[2] = fmaf(w, f2, aM[2]);
        aA[3] = fmaf(c, f3, aA[3]); aM[3] = fmaf(w, f3, aM[3]);
        aA[4] = fmaf(c, f4, aA[4]); aM[4] = fmaf(w, f4, aM[4]);
        aA[5] = fmaf(c, f5, aA[5]); aM[5] = fmaf(w, f5, aM[5]);
        aA[6] = fmaf(c, f6, aA[6]); aM[6] = fmaf(w, f6, aM[6]);
        aA[7] = fmaf(c, f7, aA[7]); aM[7] = fmaf(w, f7, aM[7]);
    }

    // reduce across the 4 quarters (all lanes end with the full sums)
    #pragma unroll
    for (int i = 0; i < 8; ++i) {
        aA[i] += __shfl_xor(aA[i], 32, 64);
        aA[i] += __shfl_xor(aA[i], 16, 64);
        aM[i] += __shfl_xor(aM[i], 32, 64);
        aM[i] += __shfl_xor(aM[i], 16, 64);
    }

    if (q4 == 0) {
        uint4 o;
        o.x = f2bf_pack(aA[0] * dcol, aA[1] * dcol);
        o.y = f2bf_pack(aA[2] * dcol, aA[3] * dcol);
        o.z = f2bf_pack(aA[4] * dcol, aA[5] * dcol);
        o.w = f2bf_pack(aA[6] * dcol, aA[7] * dcol);
        agb4[(size_t)node * 16 + sub] = o;
    } else if (q4 == 1) {
        uint4 o;
        o.x = f2bf_pack(aM[0] * im, aM[1] * im);
        o.y = f2bf_pack(aM[2] * im, aM[3] * im);
        o.z = f2bf_pack(aM[4] * im, aM[5] * im);
        o.w = f2bf_pack(aM[6] * im, aM[7] * im);
        mnb4[(size_t)node * 16 + sub] = o;
    }
}

// ---------------- fused epilogue: out = act(A1@W1 + A2@W2 + b) -----------------
template <int ACT>
__global__ __launch_bounds__(256)
void k_final(const unsigned short* __restrict__ A1,
             const unsigned short* __restrict__ A2,
             const float* __restrict__ W1, const float* __restrict__ W2,
             const float* __restrict__ bias, float* __restrict__ out, int N) {
    const int lane = threadIdx.x & 63;
    const int wv = threadIdx.x >> 6;
    const int q = lane >> 4;
    const int m = lane & 15;
    const int cg = wv * 32;
    short8 B1[2][4], B2[2][4];
    #pragma unroll
    for (int ct = 0; ct < 2; ++ct)
        #pragma unroll
        for (int c = 0; c < 4; ++c) {
            B1[ct][c] = load_bfrag(W1, cg + ct * 16 + m, c * 32 + q * 8);
            B2[ct][c] = load_bfrag(W2, cg + ct * 16 + m, c * 32 + q * 8);
        }
    const float b0 = bias[cg + m];
    const float b1 = bias[cg + 16 + m];
    const int rb = blockIdx.x * 128;
    #pragma unroll 2
    for (int rt = 0; rt < 8; ++rt) {
        int row = rb + rt * 16 + m;
        int rc = min(row, N - 1);
        const short8* a1 = (const short8*)(A1 + (size_t)rc * 128 + q * 8);
        const short8* a2 = (const short8*)(A2 + (size_t)rc * 128 + q * 8);
        float4v c0 = {0.f, 0.f, 0.f, 0.f}, c1 = {0.f, 0.f, 0.f, 0.f};
        #pragma unroll
        for (int c = 0; c < 4; ++c) {
            short8 a = a1[c * 4];
            c0 = __builtin_amdgcn_mfma_f32_16x16x32_bf16(a, B1[0][c], c0, 0, 0, 0);
            c1 = __builtin_amdgcn_mfma_f32_16x16x32_bf16(a, B1[1][c], c1, 0, 0, 0);
        }
        #pragma unroll
        for (int c = 0; c < 4; ++c) {
            short8 a = a2[c * 4];
            c0 = __builtin_amdgcn_mfma_f32_16x16x32_bf16(a, B2[0][c], c0, 0, 0, 0);
            c1 = __builtin_amdgcn_mfma_f32_16x16x32_bf16(a, B2[1][c], c1, 0, 0, 0);
        }
        #pragma unroll
        for (int r = 0; r < 4; ++r) {
            int ro = rb + rt * 16 + q * 4 + r;
            if (ro < N) {
                float v0 = c0[r] + b0;
                float v1 = c1[r] + b1;
                if (ACT == 0) { v0 = fmaxf(v0, 0.f); v1 = fmaxf(v1, 0.f); }
                else          { v0 = act_leaky_elu(v0); v1 = act_leaky_elu(v1); }
                out[(size_t)ro * 256 + cg + m]      = v0;
                out[(size_t)ro * 256 + cg + 16 + m] = v1;
            }
        }
    }
}

extern "C" void kernel_launch(void* const* d_in, const int* in_sizes, int n_in,
                              void* d_out, int out_size, void* d_ws, size_t ws_size,
                              hipStream_t stream) {
    const float* x    = (const float*)d_in[0];
    const int*   ei   = (const int*)d_in[1];
    const float* ew   = (const float*)d_in[2];
    const float* Wpre = (const float*)d_in[3];
    const float* bpre = (const float*)d_in[4];
    const float* Wai  = (const float*)d_in[5];
    const float* War  = (const float*)d_in[6];
    const float* ab   = (const float*)d_in[7];
    const float* Wsl  = (const float*)d_in[8];
    const float* bsl  = (const float*)d_in[9];
    const float* Wsr  = (const float*)d_in[10];

    const int N = in_sizes[0] / 128;
    const int E = in_sizes[2];
    const size_t NF = (size_t)N * 128;

    unsigned short* hb  = (unsigned short*)d_ws;  // NF bf16
    unsigned short* agb = hb + NF;                // NF bf16
    unsigned short* mnb = agb + NF;               // NF bf16
    float* dis  = (float*)(mnb + NF);             // N
    int*   cnti = (int*)(dis + N);                // N+1 (zeroed)
    int*   rowp = cnti + (N + 1);                 // N+1
    int*   blks = rowp + (N + 1);                 // 128
    int*   rank = blks + 128;                     // E
    void*  recs = (void*)(rank + E);              // E uints (packed) or E int2

    const bool packed = (N <= (1 << 17));

    const int ge = (E + 255) / 256;
    const int gv = (N + 255) / 256;
    const int gd = (N + 127) / 128;

    hipMemsetAsync(cnti, 0, (N + 1) * sizeof(int), stream);
    k_cnt<<<ge, 256, 0, stream>>>(ei, cnti, rank, E);

    const int ns = N + 1;
    const int nb = (ns + 1023) / 1024;
    k_scan1<<<nb, 256, 0, stream>>>(cnti, rowp, blks, ns);
    k_scan2<<<1, 128, 0, stream>>>(blks, nb);
    k_scan3<<<nb, 256, 0, stream>>>(rowp, blks, ns);

    if (packed) {
        k_scatterP<<<ge, 256, 0, stream>>>(ei, ew, rowp, rank, (unsigned*)recs, E);
        k_degsum<true><<<gv, 256, 0, stream>>>(rowp, recs, dis, N);
    } else {
        k_scatterW<<<ge, 256, 0, stream>>>(ei, ew, rowp, rank, (int2*)recs, E);
        k_degsum<false><<<gv, 256, 0, stream>>>(rowp, recs, dis, N);
    }

    k_pre<<<gd, 256, 0, stream>>>(x, Wpre, bpre, hb, N);

    if (packed)
        k_pull<true><<<(N + 3) / 4, 256, 0, stream>>>(rowp, recs, dis,
            (const uint4*)hb, (uint4*)agb, (uint4*)mnb, N);
    else
        k_pull<false><<<(N + 3) / 4, 256, 0, stream>>>(rowp, recs, dis,
            (const uint4*)hb, (uint4*)agb, (uint4*)mnb, N);

    float* out = (float*)d_out;
    k_final<0><<<gd, 256, 0, stream>>>(agb, hb, Wai, War, ab, out, N);
    k_final<1><<<gd, 256, 0, stream>>>(mnb, hb, Wsl, Wsr, bsl, out + 128, N);
}